// Round 1
// baseline (5582.739 us; speedup 1.0000x reference)
//
#include <hip/hip_runtime.h>
#include <cmath>

#define HID 128

// ---------------- utility kernels ----------------

__global__ void fill_kernel(float* p, float v, int n) {
  int i = blockIdx.x * 256 + threadIdx.x;
  if (i < n) p[i] = v;
}

__global__ void init_bias_kernel(float* __restrict__ x, const float* __restrict__ b, int nrows) {
  int i = blockIdx.x * 256 + threadIdx.x;
  if (i < nrows * HID) x[i] = b[i & 127];
}

__global__ void init_bias2_kernel(float* __restrict__ x, const float* __restrict__ b1,
                                  const float* __restrict__ b2, int nrows) {
  int i = blockIdx.x * 256 + threadIdx.x;
  if (i < nrows * HID) x[i] = b1[i & 127] + b2[i & 127];
}

__global__ void relu_kernel(float* x, int n) {
  int i = blockIdx.x * 256 + threadIdx.x;
  if (i < n) x[i] = fmaxf(x[i], 0.f);
}

// v[g][k] = sum_c W[g][k][c] * a[g][c]   (g = rel*2 + layer, 8 groups)
__global__ void compute_v_kernel(const float* __restrict__ W, const float* __restrict__ a,
                                 float* __restrict__ v) {
  int g = blockIdx.x, k = threadIdx.x;
  const float* Wg = W + g * 16384;
  const float* ag = a + g * 128;
  float s = 0.f;
  for (int c = 0; c < 128; ++c) s = fmaf(Wg[k * 128 + c], ag[c], s);
  v[g * 128 + k] = s;
}

// out[i] = dot(X[i,:], v)   (one wave per row)
__global__ void matvec128_kernel(const float* __restrict__ X, const float* __restrict__ v,
                                 float* __restrict__ out, int N) {
  __shared__ float vl[128];
  int tid = threadIdx.x;
  if (tid < 128) vl[tid] = v[tid];
  __syncthreads();
  int wave = tid >> 6, lane = tid & 63;
  int row = blockIdx.x * 4 + wave;
  if (row >= N) return;
  float s = X[row * 128 + lane] * vl[lane] + X[row * 128 + 64 + lane] * vl[64 + lane];
  for (int off = 32; off >= 1; off >>= 1) s += __shfl_down(s, off);
  if (lane == 0) out[row] = s;
}

// Y[N,128] = X[N,128] @ W[128,128]; 32-row tile, 4x4 register blocking per thread
__global__ __launch_bounds__(256) void gemm128_kernel(const float* __restrict__ X,
                                                      const float* __restrict__ W,
                                                      float* __restrict__ Y, int N) {
  __shared__ float Wl[16384];
  __shared__ float Xl[32][128];
  int tid = threadIdx.x;
  for (int i = tid; i < 16384; i += 256) Wl[i] = W[i];
  int row0 = blockIdx.x * 32;
  for (int i = tid; i < 32 * 128; i += 256) {
    int r = i >> 7, c = i & 127;
    int gr = row0 + r;
    Xl[r][c] = (gr < N) ? X[gr * 128 + c] : 0.f;
  }
  __syncthreads();
  int cg = tid & 31, rg = tid >> 5;  // cols cg+{0,32,64,96}, rows rg*4..+3
  float acc[4][4] = {};
  for (int k = 0; k < 128; ++k) {
    float w0 = Wl[k * 128 + cg];
    float w1 = Wl[k * 128 + cg + 32];
    float w2 = Wl[k * 128 + cg + 64];
    float w3 = Wl[k * 128 + cg + 96];
#pragma unroll
    for (int i = 0; i < 4; ++i) {
      float xv = Xl[rg * 4 + i][k];
      acc[i][0] = fmaf(xv, w0, acc[i][0]);
      acc[i][1] = fmaf(xv, w1, acc[i][1]);
      acc[i][2] = fmaf(xv, w2, acc[i][2]);
      acc[i][3] = fmaf(xv, w3, acc[i][3]);
    }
  }
#pragma unroll
  for (int i = 0; i < 4; ++i) {
    int gr = row0 + rg * 4 + i;
    if (gr < N) {
      Y[gr * 128 + cg]      = acc[i][0];
      Y[gr * 128 + cg + 32] = acc[i][1];
      Y[gr * 128 + cg + 64] = acc[i][2];
      Y[gr * 128 + cg + 96] = acc[i][3];
    }
  }
}

// ---------------- edge kernels ----------------

// e = leakyrelu(as[src]+ad[dst]); store to p; atomicMax m[dst]
__global__ void edge_max_kernel(const int* __restrict__ src, const int* __restrict__ dst,
                                const float* __restrict__ as_, const float* __restrict__ ad_,
                                float* __restrict__ m, float* __restrict__ p, int E) {
  int e = blockIdx.x * 256 + threadIdx.x;
  if (e >= E) return;
  float v = as_[src[e]] + ad_[dst[e]];
  v = v > 0.f ? v : 0.2f * v;
  p[e] = v;
  int d = dst[e];
  if (v >= 0.f) atomicMax((int*)(m + d), __float_as_int(v));
  else          atomicMin((unsigned int*)(m + d), (unsigned int)__float_as_int(v));
}

// p = exp(e - m[dst]); atomicAdd z[dst]
__global__ void edge_exp_kernel(const int* __restrict__ dst, const float* __restrict__ m,
                                float* __restrict__ p, float* __restrict__ z, int E) {
  int e = blockIdx.x * 256 + threadIdx.x;
  if (e >= E) return;
  int d = dst[e];
  float v = expf(p[e] - m[d]);
  p[e] = v;
  atomicAdd(z + d, v);
}

// out[dst] += (p/z[dst]) * hs[src]; 128 threads per edge, 2 edges per block
__global__ void edge_aggr_kernel(const int* __restrict__ src, const int* __restrict__ dst,
                                 const float* __restrict__ p, const float* __restrict__ z,
                                 const float* __restrict__ hs, float* __restrict__ out, int E) {
  int t = threadIdx.x;
  int e = blockIdx.x * 2 + (t >> 7);
  if (e >= E) return;
  int c = t & 127;
  int s = src[e], d = dst[e];
  float w = p[e] / fmaxf(z[d], 1e-16f);
  atomicAdd(&out[d * 128 + c], w * hs[s * 128 + c]);
}

// ---------------- head ----------------

// feat[c] += sum_rows relu(X@W + b)[row][c]
__global__ __launch_bounds__(256) void head_sum_kernel(const float* __restrict__ X,
                                                       const float* __restrict__ W,
                                                       const float* __restrict__ b,
                                                       float* __restrict__ feat, int N) {
  __shared__ float Wl[16384];
  __shared__ float Xl[32][128];
  __shared__ float colsum[128];
  int tid = threadIdx.x;
  for (int i = tid; i < 16384; i += 256) Wl[i] = W[i];
  int row0 = blockIdx.x * 32;
  for (int i = tid; i < 32 * 128; i += 256) {
    int r = i >> 7, c = i & 127;
    int gr = row0 + r;
    Xl[r][c] = (gr < N) ? X[gr * 128 + c] : 0.f;
  }
  if (tid < 128) colsum[tid] = 0.f;
  __syncthreads();
  int cg = tid & 31, rg = tid >> 5;
  float acc[4][4] = {};
  for (int k = 0; k < 128; ++k) {
    float w0 = Wl[k * 128 + cg];
    float w1 = Wl[k * 128 + cg + 32];
    float w2 = Wl[k * 128 + cg + 64];
    float w3 = Wl[k * 128 + cg + 96];
#pragma unroll
    for (int i = 0; i < 4; ++i) {
      float xv = Xl[rg * 4 + i][k];
      acc[i][0] = fmaf(xv, w0, acc[i][0]);
      acc[i][1] = fmaf(xv, w1, acc[i][1]);
      acc[i][2] = fmaf(xv, w2, acc[i][2]);
      acc[i][3] = fmaf(xv, w3, acc[i][3]);
    }
  }
  float part[4] = {0.f, 0.f, 0.f, 0.f};
#pragma unroll
  for (int i = 0; i < 4; ++i) {
    int gr = row0 + rg * 4 + i;
    if (gr < N) {
      part[0] += fmaxf(acc[i][0] + b[cg], 0.f);
      part[1] += fmaxf(acc[i][1] + b[cg + 32], 0.f);
      part[2] += fmaxf(acc[i][2] + b[cg + 64], 0.f);
      part[3] += fmaxf(acc[i][3] + b[cg + 96], 0.f);
    }
  }
  atomicAdd(&colsum[cg], part[0]);
  atomicAdd(&colsum[cg + 32], part[1]);
  atomicAdd(&colsum[cg + 64], part[2]);
  atomicAdd(&colsum[cg + 96], part[3]);
  __syncthreads();
  if (tid < 128) atomicAdd(&feat[tid], colsum[tid]);
}

__global__ void final_fc_kernel(const float* __restrict__ fa, const float* __restrict__ frs,
                                const float* __restrict__ frd, const float* __restrict__ Wfc,
                                const float* __restrict__ bfc, float* __restrict__ out) {
  __shared__ float pooled[128];
  int t = threadIdx.x;
  if (t < 128)
    pooled[t] = (fa[t] * (1.f / 100000.f) + frs[t] * (1.f / 20000.f) + frd[t] * (1.f / 50000.f)) *
                (1.f / 3.f);
  __syncthreads();
  if (t < 64) {
    float s = bfc[t];
    for (int c = 0; c < 128; ++c) s = fmaf(pooled[c], Wfc[c * 64 + t], s);
    out[t] = s;
  }
}

// ---------------- orchestration ----------------

extern "C" void kernel_launch(void* const* d_in, const int* in_sizes, int n_in,
                              void* d_out, int out_size, void* d_ws, size_t ws_size,
                              hipStream_t stream) {
  const int N_ACT = 100000, N_RS = 20000, N_RD = 50000;
  const int E_F = 1600000, E_RS = 800000, E_RD = 800000, E_HRD = 800000;

  const float* x_act = (const float*)d_in[0];
  const float* x_rs  = (const float*)d_in[1];
  const float* x_rd  = (const float*)d_in[2];
  const int* ef_src  = (const int*)d_in[3];
  const int* ef_dst  = (const int*)d_in[4];
  const int* ers_src = (const int*)d_in[5];
  const int* ers_dst = (const int*)d_in[6];
  const int* erd_src = (const int*)d_in[7];
  const int* erd_dst = (const int*)d_in[8];
  const int* ehrd_src = (const int*)d_in[9];
  const int* ehrd_dst = (const int*)d_in[10];
  const float* Wsrc   = (const float*)d_in[11];
  const float* Wdst   = (const float*)d_in[12];
  const float* att_src = (const float*)d_in[13];
  const float* att_dst = (const float*)d_in[14];
  const float* b_gat  = (const float*)d_in[15];
  const float* W_ln   = (const float*)d_in[16];
  const float* b_ln   = (const float*)d_in[17];
  const float* W_fc   = (const float*)d_in[18];
  const float* b_fc   = (const float*)d_in[19];
  float* out = (float*)d_out;

  float* w = (float*)d_ws;
  float* xaA = w;  w += (size_t)N_ACT * 128;
  float* xaB = w;  w += (size_t)N_ACT * 128;
  float* xrsA = w; w += (size_t)N_RS * 128;
  float* xrsB = w; w += (size_t)N_RS * 128;
  float* xrdA = w; w += (size_t)N_RD * 128;
  float* xrdB = w; w += (size_t)N_RD * 128;
  float* hs = w;   w += (size_t)N_ACT * 128;
  float* as_ = w;  w += N_ACT;
  float* ad_ = w;  w += N_ACT;
  float* mbuf = w; w += N_ACT;
  float* zbuf = w; w += N_ACT;
  float* pbuf = w; w += E_F;
  float* vs = w;   w += 1024;
  float* vd = w;   w += 1024;
  float* feats = w; w += 384;

  compute_v_kernel<<<8, 128, 0, stream>>>(Wsrc, att_src, vs);
  compute_v_kernel<<<8, 128, 0, stream>>>(Wdst, att_dst, vd);

  const float* xa = x_act;
  const float* xrs = x_rs;
  const float* xrd = x_rd;

  for (int L = 0; L < 2; ++L) {
    float* na  = (L == 0) ? xaA : xaB;
    float* nrs = (L == 0) ? xrsA : xrsB;
    float* nrd = (L == 0) ? xrdA : xrdB;

    init_bias_kernel<<<(N_ACT * 128 + 255) / 256, 256, 0, stream>>>(na, b_gat + (0 * 2 + L) * 128, N_ACT);
    init_bias_kernel<<<(N_RS * 128 + 255) / 256, 256, 0, stream>>>(nrs, b_gat + (1 * 2 + L) * 128, N_RS);
    init_bias2_kernel<<<(N_RD * 128 + 255) / 256, 256, 0, stream>>>(
        nrd, b_gat + (2 * 2 + L) * 128, b_gat + (3 * 2 + L) * 128, N_RD);

    struct Rel {
      const float* xs; int ns;
      const float* xd; int nd;
      const int* src; const int* dst; int ne;
      float* outb;
    } rels[4] = {
      {xa, N_ACT, xa, N_ACT, ef_src, ef_dst, E_F, na},
      {xa, N_ACT, xrs, N_RS, ers_src, ers_dst, E_RS, nrs},
      {xrd, N_RD, xrd, N_RD, erd_src, erd_dst, E_RD, nrd},
      {xa, N_ACT, xrd, N_RD, ehrd_src, ehrd_dst, E_HRD, nrd},
    };

    for (int r = 0; r < 4; ++r) {
      const Rel& R = rels[r];
      int g = r * 2 + L;
      gemm128_kernel<<<(R.ns + 31) / 32, 256, 0, stream>>>(R.xs, Wsrc + (size_t)g * 16384, hs, R.ns);
      matvec128_kernel<<<(R.ns + 3) / 4, 256, 0, stream>>>(R.xs, vs + g * 128, as_, R.ns);
      matvec128_kernel<<<(R.nd + 3) / 4, 256, 0, stream>>>(R.xd, vd + g * 128, ad_, R.nd);
      fill_kernel<<<(R.nd + 255) / 256, 256, 0, stream>>>(mbuf, -__builtin_huge_valf(), R.nd);
      fill_kernel<<<(R.nd + 255) / 256, 256, 0, stream>>>(zbuf, 0.f, R.nd);
      edge_max_kernel<<<(R.ne + 255) / 256, 256, 0, stream>>>(R.src, R.dst, as_, ad_, mbuf, pbuf, R.ne);
      edge_exp_kernel<<<(R.ne + 255) / 256, 256, 0, stream>>>(R.dst, mbuf, pbuf, zbuf, R.ne);
      edge_aggr_kernel<<<(R.ne + 1) / 2, 256, 0, stream>>>(R.src, R.dst, pbuf, zbuf, hs, R.outb, R.ne);
    }

    relu_kernel<<<(N_ACT * 128 + 255) / 256, 256, 0, stream>>>(na, N_ACT * 128);
    relu_kernel<<<(N_RS * 128 + 255) / 256, 256, 0, stream>>>(nrs, N_RS * 128);
    relu_kernel<<<(N_RD * 128 + 255) / 256, 256, 0, stream>>>(nrd, N_RD * 128);

    xa = na; xrs = nrs; xrd = nrd;
  }

  fill_kernel<<<2, 256, 0, stream>>>(feats, 0.f, 384);
  head_sum_kernel<<<(N_ACT + 31) / 32, 256, 0, stream>>>(xa, W_ln, b_ln, feats, N_ACT);
  head_sum_kernel<<<(N_RS + 31) / 32, 256, 0, stream>>>(xrs, W_ln, b_ln, feats + 128, N_RS);
  head_sum_kernel<<<(N_RD + 31) / 32, 256, 0, stream>>>(xrd, W_ln, b_ln, feats + 256, N_RD);
  final_fc_kernel<<<1, 128, 0, stream>>>(feats, feats + 128, feats + 256, W_fc, b_fc, out);
}

// Round 2
// 1966.477 us; speedup vs baseline: 2.8390x; 2.8390x over previous
//
#include <hip/hip_runtime.h>
#include <cmath>

#define HID 128

// ---------------- utility kernels ----------------

__global__ void fill_f_kernel(float* p, float v, int n) {
  int i = blockIdx.x * 256 + threadIdx.x;
  if (i < n) p[i] = v;
}

__global__ void fill_i_kernel(int* p, int v, int n) {
  int i = blockIdx.x * 256 + threadIdx.x;
  if (i < n) p[i] = v;
}

// v[g][c] = sum_k W[g][c][k] * a[g][k]   (g = rel*2 + layer, 8 groups)
__global__ void compute_v_kernel(const float* __restrict__ W, const float* __restrict__ a,
                                 float* __restrict__ v) {
  int g = blockIdx.x, k = threadIdx.x;
  const float* Wg = W + g * 16384;
  const float* ag = a + g * 128;
  float s = 0.f;
  for (int c = 0; c < 128; ++c) s = fmaf(Wg[k * 128 + c], ag[c], s);
  v[g * 128 + k] = s;
}

// out[i] = dot(X[i,:], v)   (one wave per row)
__global__ void matvec128_kernel(const float* __restrict__ X, const float* __restrict__ v,
                                 float* __restrict__ out, int N) {
  __shared__ float vl[128];
  int tid = threadIdx.x;
  if (tid < 128) vl[tid] = v[tid];
  __syncthreads();
  int wave = tid >> 6, lane = tid & 63;
  int row = blockIdx.x * 4 + wave;
  if (row >= N) return;
  float s = X[(size_t)row * 128 + lane] * vl[lane] +
            X[(size_t)row * 128 + 64 + lane] * vl[64 + lane];
  for (int off = 32; off >= 1; off >>= 1) s += __shfl_down(s, off);
  if (lane == 0) out[row] = s;
}

// ---------------- CSR build (counting sort by dst) ----------------

__global__ void hist_kernel(const int* __restrict__ dst, int* __restrict__ cnt, int E) {
  int e = blockIdx.x * 256 + threadIdx.x;
  if (e < E) atomicAdd(&cnt[dst[e]], 1);
}

__global__ void partial_sum_kernel(const int* __restrict__ cnt, int* __restrict__ part, int n) {
  __shared__ int tmp[256];
  int i = blockIdx.x * 256 + threadIdx.x;
  tmp[threadIdx.x] = (i < n) ? cnt[i] : 0;
  __syncthreads();
  for (int off = 128; off; off >>= 1) {
    if (threadIdx.x < off) tmp[threadIdx.x] += tmp[threadIdx.x + off];
    __syncthreads();
  }
  if (threadIdx.x == 0) part[blockIdx.x] = tmp[0];
}

__global__ void scan_part_kernel(int* part, int nb) {
  if (threadIdx.x == 0 && blockIdx.x == 0) {
    int run = 0;
    for (int b = 0; b < nb; ++b) {
      int t = part[b];
      part[b] = run;
      run += t;
    }
  }
}

__global__ void scan_final_kernel(const int* __restrict__ cnt, const int* __restrict__ part,
                                  int* __restrict__ rowptr, int n) {
  __shared__ int tmp[256];
  int tid = threadIdx.x;
  int i = blockIdx.x * 256 + tid;
  int v = (i < n) ? cnt[i] : 0;
  tmp[tid] = v;
  __syncthreads();
  for (int off = 1; off < 256; off <<= 1) {
    int t = (tid >= off) ? tmp[tid - off] : 0;
    __syncthreads();
    tmp[tid] += t;
    __syncthreads();
  }
  if (i <= n) rowptr[i] = part[blockIdx.x] + tmp[tid] - v;  // exclusive; i==n -> total E
}

__global__ void scatter_kernel(const int* __restrict__ src, const int* __restrict__ dst,
                               const int* __restrict__ rowptr, int* __restrict__ fill,
                               int* __restrict__ csr, int E) {
  int e = blockIdx.x * 256 + threadIdx.x;
  if (e >= E) return;
  int d = dst[e];
  int pos = rowptr[d] + atomicAdd(&fill[d], 1);
  csr[pos] = src[e];
}

// ---------------- GAT aggregation: one wave per dst node ----------------
// agg[d] = sum_j softmax_j(leakyrelu(as[src_j]+ad[d])) * X[src_j]
__global__ __launch_bounds__(256) void gat_aggr_kernel(
    const int* __restrict__ rowptr, const int* __restrict__ csr,
    const float* __restrict__ as_, const float* __restrict__ ad_,
    const float* __restrict__ X, float* __restrict__ agg, int n_dst) {
  int wave = threadIdx.x >> 6, lane = threadIdx.x & 63;
  int d = blockIdx.x * 4 + wave;
  if (d >= n_dst) return;
  int beg = rowptr[d], end = rowptr[d + 1];
  float ad = ad_[d];
  float m = -INFINITY, z = 0.f;
  float ax = 0.f, ay = 0.f;
  for (int c0 = beg; c0 < end; c0 += 64) {
    int j = c0 + lane;
    int s = (j < end) ? csr[j] : 0;
    float e;
    if (j < end) {
      float t = as_[s] + ad;
      e = t > 0.f ? t : 0.2f * t;
    } else {
      e = -INFINITY;
    }
    // chunk max
    float cm = e;
#pragma unroll
    for (int off = 32; off; off >>= 1) cm = fmaxf(cm, __shfl_xor(cm, off));
    float mn = fmaxf(m, cm);
    float p = (j < end) ? expf(e - mn) : 0.f;
    float ps = p;
#pragma unroll
    for (int off = 32; off; off >>= 1) ps += __shfl_xor(ps, off);
    float scale = expf(m - mn);  // first chunk: exp(-inf)=0
    ax *= scale;
    ay *= scale;
    z = z * scale + ps;
    m = mn;
    int cnt = min(64, end - c0);
#pragma unroll 4
    for (int k = 0; k < cnt; ++k) {
      float w = __shfl(p, k);
      int s2 = __shfl(s, k);
      const float2 xv = *reinterpret_cast<const float2*>(X + (size_t)s2 * 128 + 2 * lane);
      ax = fmaf(w, xv.x, ax);
      ay = fmaf(w, xv.y, ay);
    }
  }
  float inv = 1.f / fmaxf(z, 1e-16f);
  agg[(size_t)d * 128 + 2 * lane] = ax * inv;
  agg[(size_t)d * 128 + 2 * lane + 1] = ay * inv;
}

// ---------------- GEMM: Y = [beta*Y +] X@W + bias [, relu] ----------------
// 64-row tile, K chunked by 32; 24.8 KB LDS
template <int BETA, int RELU>
__global__ __launch_bounds__(256) void gemm64_kernel(const float* __restrict__ X,
                                                     const float* __restrict__ W,
                                                     const float* __restrict__ bias,
                                                     float* __restrict__ Y, int N) {
  __shared__ float Wl[32 * 128];
  __shared__ float Xl[64 * 33];
  int tid = threadIdx.x;
  int row0 = blockIdx.x * 64;
  int cg = tid & 31, rg = tid >> 5;
  float acc[8][4] = {};
  for (int kb = 0; kb < 4; ++kb) {
    __syncthreads();
    for (int i = tid; i < 4096; i += 256) Wl[i] = W[kb * 4096 + i];
    for (int i = tid; i < 2048; i += 256) {
      int r = i >> 5, k = i & 31;
      int gr = row0 + r;
      Xl[r * 33 + k] = (gr < N) ? X[(size_t)gr * 128 + kb * 32 + k] : 0.f;
    }
    __syncthreads();
    for (int k = 0; k < 32; ++k) {
      float w0 = Wl[k * 128 + cg];
      float w1 = Wl[k * 128 + cg + 32];
      float w2 = Wl[k * 128 + cg + 64];
      float w3 = Wl[k * 128 + cg + 96];
#pragma unroll
      for (int i = 0; i < 8; ++i) {
        float xv = Xl[(rg * 8 + i) * 33 + k];
        acc[i][0] = fmaf(xv, w0, acc[i][0]);
        acc[i][1] = fmaf(xv, w1, acc[i][1]);
        acc[i][2] = fmaf(xv, w2, acc[i][2]);
        acc[i][3] = fmaf(xv, w3, acc[i][3]);
      }
    }
  }
  float b0 = bias[cg], b1 = bias[cg + 32], b2 = bias[cg + 64], b3 = bias[cg + 96];
#pragma unroll
  for (int i = 0; i < 8; ++i) {
    int gr = row0 + rg * 8 + i;
    if (gr < N) {
      size_t base = (size_t)gr * 128;
      float o0 = acc[i][0] + b0;
      float o1 = acc[i][1] + b1;
      float o2 = acc[i][2] + b2;
      float o3 = acc[i][3] + b3;
      if (BETA) {
        o0 += Y[base + cg];
        o1 += Y[base + cg + 32];
        o2 += Y[base + cg + 64];
        o3 += Y[base + cg + 96];
      }
      if (RELU) {
        o0 = fmaxf(o0, 0.f);
        o1 = fmaxf(o1, 0.f);
        o2 = fmaxf(o2, 0.f);
        o3 = fmaxf(o3, 0.f);
      }
      Y[base + cg] = o0;
      Y[base + cg + 32] = o1;
      Y[base + cg + 64] = o2;
      Y[base + cg + 96] = o3;
    }
  }
}

// ---------------- head: feat[c] += sum_rows relu(X@W + b)[row][c] ----------------
__global__ __launch_bounds__(256) void head_sum_kernel(const float* __restrict__ X,
                                                       const float* __restrict__ W,
                                                       const float* __restrict__ b,
                                                       float* __restrict__ feat, int N) {
  __shared__ float Wl[32 * 128];
  __shared__ float Xl[64 * 33];
  __shared__ float colsum[128];
  int tid = threadIdx.x;
  int row0 = blockIdx.x * 64;
  int cg = tid & 31, rg = tid >> 5;
  float acc[8][4] = {};
  for (int kb = 0; kb < 4; ++kb) {
    __syncthreads();
    for (int i = tid; i < 4096; i += 256) Wl[i] = W[kb * 4096 + i];
    for (int i = tid; i < 2048; i += 256) {
      int r = i >> 5, k = i & 31;
      int gr = row0 + r;
      Xl[r * 33 + k] = (gr < N) ? X[(size_t)gr * 128 + kb * 32 + k] : 0.f;
    }
    __syncthreads();
    for (int k = 0; k < 32; ++k) {
      float w0 = Wl[k * 128 + cg];
      float w1 = Wl[k * 128 + cg + 32];
      float w2 = Wl[k * 128 + cg + 64];
      float w3 = Wl[k * 128 + cg + 96];
#pragma unroll
      for (int i = 0; i < 8; ++i) {
        float xv = Xl[(rg * 8 + i) * 33 + k];
        acc[i][0] = fmaf(xv, w0, acc[i][0]);
        acc[i][1] = fmaf(xv, w1, acc[i][1]);
        acc[i][2] = fmaf(xv, w2, acc[i][2]);
        acc[i][3] = fmaf(xv, w3, acc[i][3]);
      }
    }
  }
  if (tid < 128) colsum[tid] = 0.f;
  __syncthreads();
  float b0 = b[cg], b1 = b[cg + 32], b2 = b[cg + 64], b3 = b[cg + 96];
  float part[4] = {0.f, 0.f, 0.f, 0.f};
#pragma unroll
  for (int i = 0; i < 8; ++i) {
    int gr = row0 + rg * 8 + i;
    if (gr < N) {
      part[0] += fmaxf(acc[i][0] + b0, 0.f);
      part[1] += fmaxf(acc[i][1] + b1, 0.f);
      part[2] += fmaxf(acc[i][2] + b2, 0.f);
      part[3] += fmaxf(acc[i][3] + b3, 0.f);
    }
  }
  atomicAdd(&colsum[cg], part[0]);
  atomicAdd(&colsum[cg + 32], part[1]);
  atomicAdd(&colsum[cg + 64], part[2]);
  atomicAdd(&colsum[cg + 96], part[3]);
  __syncthreads();
  if (tid < 128) atomicAdd(&feat[tid], colsum[tid]);
}

__global__ void final_fc_kernel(const float* __restrict__ fa, const float* __restrict__ frs,
                                const float* __restrict__ frd, const float* __restrict__ Wfc,
                                const float* __restrict__ bfc, float* __restrict__ out) {
  __shared__ float pooled[128];
  int t = threadIdx.x;
  if (t < 128)
    pooled[t] = (fa[t] * (1.f / 100000.f) + frs[t] * (1.f / 20000.f) + frd[t] * (1.f / 50000.f)) *
                (1.f / 3.f);
  __syncthreads();
  if (t < 64) {
    float s = bfc[t];
    for (int c = 0; c < 128; ++c) s = fmaf(pooled[c], Wfc[c * 64 + t], s);
    out[t] = s;
  }
}

// ---------------- orchestration ----------------

extern "C" void kernel_launch(void* const* d_in, const int* in_sizes, int n_in,
                              void* d_out, int out_size, void* d_ws, size_t ws_size,
                              hipStream_t stream) {
  const int N_ACT = 100000, N_RS = 20000, N_RD = 50000;
  const int E_F = 1600000, E_RS = 800000, E_RD = 800000, E_HRD = 800000;

  const float* x_act = (const float*)d_in[0];
  const float* x_rs = (const float*)d_in[1];
  const float* x_rd = (const float*)d_in[2];
  const int* ef_src = (const int*)d_in[3];
  const int* ef_dst = (const int*)d_in[4];
  const int* ers_src = (const int*)d_in[5];
  const int* ers_dst = (const int*)d_in[6];
  const int* erd_src = (const int*)d_in[7];
  const int* erd_dst = (const int*)d_in[8];
  const int* ehrd_src = (const int*)d_in[9];
  const int* ehrd_dst = (const int*)d_in[10];
  const float* Wsrc = (const float*)d_in[11];
  const float* Wdst = (const float*)d_in[12];
  const float* att_src = (const float*)d_in[13];
  const float* att_dst = (const float*)d_in[14];
  const float* b_gat = (const float*)d_in[15];
  const float* W_ln = (const float*)d_in[16];
  const float* b_ln = (const float*)d_in[17];
  const float* W_fc = (const float*)d_in[18];
  const float* b_fc = (const float*)d_in[19];
  float* out = (float*)d_out;

  float* w = (float*)d_ws;
  float* xaA = w;  w += (size_t)N_ACT * 128;
  float* xaB = w;  w += (size_t)N_ACT * 128;
  float* xrsA = w; w += (size_t)N_RS * 128;
  float* xrsB = w; w += (size_t)N_RS * 128;
  float* xrdA = w; w += (size_t)N_RD * 128;
  float* xrdB = w; w += (size_t)N_RD * 128;
  float* agg = w;  w += (size_t)N_ACT * 128;
  float* as_ = w;  w += N_ACT;
  float* ad_ = w;  w += N_ACT;
  float* vs = w;   w += 1024;
  float* vd = w;   w += 1024;
  float* feats = w; w += 384;
  int* ip = (int*)w;
  int* rowptr_f = ip;   ip += N_ACT + 1;
  int* rowptr_rs = ip;  ip += N_RS + 1;
  int* rowptr_rd = ip;  ip += N_RD + 1;
  int* rowptr_hrd = ip; ip += N_RD + 1;
  int* csr_f = ip;      ip += E_F;
  int* csr_rs = ip;     ip += E_RS;
  int* csr_rd = ip;     ip += E_RD;
  int* csr_hrd = ip;    ip += E_HRD;
  int* cnt = ip;        ip += N_ACT;
  int* part = ip;       ip += 1024;

  // ---- build CSR for the 4 graphs (edge lists are layer-invariant) ----
  struct G {
    const int* src; const int* dst; int nd; int ne; int* rowptr; int* csr;
  } graphs[4] = {
    {ef_src, ef_dst, N_ACT, E_F, rowptr_f, csr_f},
    {ers_src, ers_dst, N_RS, E_RS, rowptr_rs, csr_rs},
    {erd_src, erd_dst, N_RD, E_RD, rowptr_rd, csr_rd},
    {ehrd_src, ehrd_dst, N_RD, E_HRD, rowptr_hrd, csr_hrd},
  };
  for (int g = 0; g < 4; ++g) {
    const G& Gr = graphs[g];
    int nb = (Gr.nd + 1 + 255) / 256;
    fill_i_kernel<<<(Gr.nd + 255) / 256, 256, 0, stream>>>(cnt, 0, Gr.nd);
    hist_kernel<<<(Gr.ne + 255) / 256, 256, 0, stream>>>(Gr.dst, cnt, Gr.ne);
    partial_sum_kernel<<<nb, 256, 0, stream>>>(cnt, part, Gr.nd);
    scan_part_kernel<<<1, 64, 0, stream>>>(part, nb);
    scan_final_kernel<<<nb, 256, 0, stream>>>(cnt, part, Gr.rowptr, Gr.nd);
    fill_i_kernel<<<(Gr.nd + 255) / 256, 256, 0, stream>>>(cnt, 0, Gr.nd);
    scatter_kernel<<<(Gr.ne + 255) / 256, 256, 0, stream>>>(Gr.src, Gr.dst, Gr.rowptr, cnt,
                                                            Gr.csr, Gr.ne);
  }

  compute_v_kernel<<<8, 128, 0, stream>>>(Wsrc, att_src, vs);
  compute_v_kernel<<<8, 128, 0, stream>>>(Wdst, att_dst, vd);

  const float* xa = x_act;
  const float* xrs = x_rs;
  const float* xrd = x_rd;

  for (int L = 0; L < 2; ++L) {
    float* na = (L == 0) ? xaA : xaB;
    float* nrs = (L == 0) ? xrsA : xrsB;
    float* nrd = (L == 0) ? xrdA : xrdB;

    struct Rel {
      const float* xs; int ns;
      const float* xd; int nd;
      const int* rowptr; const int* csr;
      float* outb; int beta; int relu;
    } rels[4] = {
      {xa, N_ACT, xa, N_ACT, rowptr_f, csr_f, na, 0, 1},
      {xa, N_ACT, xrs, N_RS, rowptr_rs, csr_rs, nrs, 0, 1},
      {xrd, N_RD, xrd, N_RD, rowptr_rd, csr_rd, nrd, 0, 0},
      {xa, N_ACT, xrd, N_RD, rowptr_hrd, csr_hrd, nrd, 1, 1},
    };

    for (int r = 0; r < 4; ++r) {
      const Rel& R = rels[r];
      int g = r * 2 + L;
      matvec128_kernel<<<(R.ns + 3) / 4, 256, 0, stream>>>(R.xs, vs + g * 128, as_, R.ns);
      matvec128_kernel<<<(R.nd + 3) / 4, 256, 0, stream>>>(R.xd, vd + g * 128, ad_, R.nd);
      gat_aggr_kernel<<<(R.nd + 3) / 4, 256, 0, stream>>>(R.rowptr, R.csr, as_, ad_, R.xs, agg,
                                                          R.nd);
      const float* bb = b_gat + g * 128;
      if (R.beta == 0 && R.relu == 1)
        gemm64_kernel<0, 1><<<(R.nd + 63) / 64, 256, 0, stream>>>(agg, Wsrc + (size_t)g * 16384,
                                                                  bb, R.outb, R.nd);
      else if (R.beta == 0 && R.relu == 0)
        gemm64_kernel<0, 0><<<(R.nd + 63) / 64, 256, 0, stream>>>(agg, Wsrc + (size_t)g * 16384,
                                                                  bb, R.outb, R.nd);
      else
        gemm64_kernel<1, 1><<<(R.nd + 63) / 64, 256, 0, stream>>>(agg, Wsrc + (size_t)g * 16384,
                                                                  bb, R.outb, R.nd);
    }

    xa = na; xrs = nrs; xrd = nrd;
  }

  fill_f_kernel<<<2, 256, 0, stream>>>(feats, 0.f, 384);
  head_sum_kernel<<<(N_ACT + 63) / 64, 256, 0, stream>>>(xa, W_ln, b_ln, feats, N_ACT);
  head_sum_kernel<<<(N_RS + 63) / 64, 256, 0, stream>>>(xrs, W_ln, b_ln, feats + 128, N_RS);
  head_sum_kernel<<<(N_RD + 63) / 64, 256, 0, stream>>>(xrd, W_ln, b_ln, feats + 256, N_RD);
  final_fc_kernel<<<1, 128, 0, stream>>>(feats, feats + 128, feats + 256, W_fc, b_fc, out);
}

// Round 3
// 1793.275 us; speedup vs baseline: 3.1132x; 1.0966x over previous
//
#include <hip/hip_runtime.h>
#include <cmath>

#define HID 128

// ---------------- utility kernels ----------------

__global__ void fill_f_kernel(float* p, float v, int n) {
  int i = blockIdx.x * 256 + threadIdx.x;
  if (i < n) p[i] = v;
}

__global__ void fill_i_kernel(int* p, int v, int n) {
  int i = blockIdx.x * 256 + threadIdx.x;
  if (i < n) p[i] = v;
}

// v[g][k] = sum_c W[g][k][c] * a[g][c]   (g = rel*2 + layer, 8 groups)
__global__ void compute_v_kernel(const float* __restrict__ W, const float* __restrict__ a,
                                 float* __restrict__ v) {
  int g = blockIdx.x, k = threadIdx.x;
  const float* Wg = W + g * 16384;
  const float* ag = a + g * 128;
  float s = 0.f;
  for (int c = 0; c < 128; ++c) s = fmaf(Wg[k * 128 + c], ag[c], s);
  v[g * 128 + k] = s;
}

// up to 4 dot products per row in ONE pass over X
template <int NV>
__global__ __launch_bounds__(256) void matvecN_kernel(
    const float* __restrict__ X, const float* __restrict__ v0, const float* __restrict__ v1,
    const float* __restrict__ v2, const float* __restrict__ v3, float* __restrict__ o0,
    float* __restrict__ o1, float* __restrict__ o2, float* __restrict__ o3, int N) {
  __shared__ float vl[NV][128];
  int tid = threadIdx.x;
  if (tid < 128) {
    vl[0][tid] = v0[tid];
    if (NV > 1) vl[1][tid] = v1[tid];
    if (NV > 2) vl[2][tid] = v2[tid];
    if (NV > 3) vl[3][tid] = v3[tid];
  }
  __syncthreads();
  int wave = tid >> 6, lane = tid & 63;
  int row = blockIdx.x * 4 + wave;
  if (row >= N) return;
  float x0 = X[(size_t)row * 128 + lane];
  float x1 = X[(size_t)row * 128 + 64 + lane];
  float a[NV];
#pragma unroll
  for (int j = 0; j < NV; ++j) a[j] = x0 * vl[j][lane] + x1 * vl[j][64 + lane];
#pragma unroll
  for (int j = 0; j < NV; ++j) {
    float s = a[j];
#pragma unroll
    for (int off = 32; off >= 1; off >>= 1) s += __shfl_down(s, off);
    a[j] = s;
  }
  if (lane == 0) {
    o0[row] = a[0];
    if (NV > 1) o1[row] = a[1];
    if (NV > 2) o2[row] = a[2];
    if (NV > 3) o3[row] = a[3];
  }
}

// ---------------- CSR build (counting sort by dst) ----------------

__global__ void hist_kernel(const int* __restrict__ dst, int* __restrict__ cnt, int E) {
  int e = blockIdx.x * 256 + threadIdx.x;
  if (e < E) atomicAdd(&cnt[dst[e]], 1);
}

__global__ void partial_sum_kernel(const int* __restrict__ cnt, int* __restrict__ part, int n) {
  __shared__ int tmp[256];
  int i = blockIdx.x * 256 + threadIdx.x;
  tmp[threadIdx.x] = (i < n) ? cnt[i] : 0;
  __syncthreads();
  for (int off = 128; off; off >>= 1) {
    if (threadIdx.x < off) tmp[threadIdx.x] += tmp[threadIdx.x + off];
    __syncthreads();
  }
  if (threadIdx.x == 0) part[blockIdx.x] = tmp[0];
}

__global__ void scan_part_kernel(int* part, int nb) {
  if (threadIdx.x == 0 && blockIdx.x == 0) {
    int run = 0;
    for (int b = 0; b < nb; ++b) {
      int t = part[b];
      part[b] = run;
      run += t;
    }
  }
}

__global__ void scan_final_kernel(const int* __restrict__ cnt, const int* __restrict__ part,
                                  int* __restrict__ rowptr, int n) {
  __shared__ int tmp[256];
  int tid = threadIdx.x;
  int i = blockIdx.x * 256 + tid;
  int v = (i < n) ? cnt[i] : 0;
  tmp[tid] = v;
  __syncthreads();
  for (int off = 1; off < 256; off <<= 1) {
    int t = (tid >= off) ? tmp[tid - off] : 0;
    __syncthreads();
    tmp[tid] += t;
    __syncthreads();
  }
  if (i <= n) rowptr[i] = part[blockIdx.x] + tmp[tid] - v;  // exclusive; i==n -> total E
}

__global__ void scatter_kernel(const int* __restrict__ src, const int* __restrict__ dst,
                               const int* __restrict__ rowptr, int* __restrict__ fill,
                               int* __restrict__ csr, int E) {
  int e = blockIdx.x * 256 + threadIdx.x;
  if (e >= E) return;
  int d = dst[e];
  int pos = rowptr[d] + atomicAdd(&fill[d], 1);
  csr[pos] = src[e];
}

// ---------------- GAT aggregation: one wave per dst node, 2 edges/iter ----------------
// agg[d] = sum_j softmax_j(leakyrelu(as[src_j]+ad[d])) * X[src_j]
__global__ __launch_bounds__(256) void gat_aggr_kernel(
    const int* __restrict__ rowptr, const int* __restrict__ csr, const float* __restrict__ as_,
    const float* __restrict__ ad_, const float* __restrict__ X, float* __restrict__ agg,
    int n_dst) {
  int wave = threadIdx.x >> 6, lane = threadIdx.x & 63;
  int half = lane >> 5, lc = lane & 31;
  int d = blockIdx.x * 4 + wave;
  if (d >= n_dst) return;
  int beg = rowptr[d], end = rowptr[d + 1];
  float ad = ad_[d];
  float m = -INFINITY, z = 0.f;
  float a0 = 0.f, a1 = 0.f, a2 = 0.f, a3 = 0.f;
  for (int c0 = beg; c0 < end; c0 += 64) {
    int j = c0 + lane;
    int s = 0;
    float e = -INFINITY;
    if (j < end) {
      s = csr[j];
      float t = as_[s] + ad;
      e = t > 0.f ? t : 0.2f * t;
    }
    float cm = e;
#pragma unroll
    for (int off = 32; off; off >>= 1) cm = fmaxf(cm, __shfl_xor(cm, off));
    float mn = fmaxf(m, cm);
    float p = (j < end) ? expf(e - mn) : 0.f;
    float ps = p;
#pragma unroll
    for (int off = 32; off; off >>= 1) ps += __shfl_xor(ps, off);
    float scale = expf(m - mn);  // first chunk: exp(-inf)=0, accs are 0 anyway
    a0 *= scale; a1 *= scale; a2 *= scale; a3 *= scale;
    z = z * scale + ps;
    m = mn;
    int cnt = min(64, end - c0);
#pragma unroll 4
    for (int k = 0; k < cnt; k += 2) {
      int idx = k + half;  // low half: edge k, high half: edge k+1
      float w = __shfl(p, idx);
      int s2 = __shfl(s, idx);
      if (idx < cnt) {
        const float4 xv = *reinterpret_cast<const float4*>(X + (size_t)s2 * 128 + lc * 4);
        a0 = fmaf(w, xv.x, a0);
        a1 = fmaf(w, xv.y, a1);
        a2 = fmaf(w, xv.z, a2);
        a3 = fmaf(w, xv.w, a3);
      }
    }
  }
  // combine the two halves (same columns lc*4..lc*4+3)
  a0 += __shfl_xor(a0, 32);
  a1 += __shfl_xor(a1, 32);
  a2 += __shfl_xor(a2, 32);
  a3 += __shfl_xor(a3, 32);
  if (half == 0) {
    float inv = 1.f / fmaxf(z, 1e-16f);
    float4 r;
    r.x = a0 * inv; r.y = a1 * inv; r.z = a2 * inv; r.w = a3 * inv;
    *reinterpret_cast<float4*>(agg + (size_t)d * 128 + lc * 4) = r;
  }
}

// ---------------- GEMM: Y = [Y +] X@W + bias [, relu] ----------------
template <int BETA, int RELU>
__global__ __launch_bounds__(256) void gemm64_kernel(const float* __restrict__ X,
                                                     const float* __restrict__ W,
                                                     const float* __restrict__ bias,
                                                     float* __restrict__ Y, int N) {
  __shared__ float Wl[32 * 128];
  __shared__ float Xl[64 * 33];
  int tid = threadIdx.x;
  int row0 = blockIdx.x * 64;
  int cg = tid & 31, rg = tid >> 5;
  float acc[8][4] = {};
  for (int kb = 0; kb < 4; ++kb) {
    __syncthreads();
    for (int i = tid; i < 4096; i += 256) Wl[i] = W[kb * 4096 + i];
    for (int i = tid; i < 2048; i += 256) {
      int r = i >> 5, k = i & 31;
      int gr = row0 + r;
      Xl[r * 33 + k] = (gr < N) ? X[(size_t)gr * 128 + kb * 32 + k] : 0.f;
    }
    __syncthreads();
    for (int k = 0; k < 32; ++k) {
      float w0 = Wl[k * 128 + cg];
      float w1 = Wl[k * 128 + cg + 32];
      float w2 = Wl[k * 128 + cg + 64];
      float w3 = Wl[k * 128 + cg + 96];
#pragma unroll
      for (int i = 0; i < 8; ++i) {
        float xv = Xl[(rg * 8 + i) * 33 + k];
        acc[i][0] = fmaf(xv, w0, acc[i][0]);
        acc[i][1] = fmaf(xv, w1, acc[i][1]);
        acc[i][2] = fmaf(xv, w2, acc[i][2]);
        acc[i][3] = fmaf(xv, w3, acc[i][3]);
      }
    }
  }
  float b0 = bias[cg], b1 = bias[cg + 32], b2 = bias[cg + 64], b3 = bias[cg + 96];
#pragma unroll
  for (int i = 0; i < 8; ++i) {
    int gr = row0 + rg * 8 + i;
    if (gr < N) {
      size_t base = (size_t)gr * 128;
      float o0 = acc[i][0] + b0;
      float o1 = acc[i][1] + b1;
      float o2 = acc[i][2] + b2;
      float o3 = acc[i][3] + b3;
      if (BETA) {
        o0 += Y[base + cg];
        o1 += Y[base + cg + 32];
        o2 += Y[base + cg + 64];
        o3 += Y[base + cg + 96];
      }
      if (RELU) {
        o0 = fmaxf(o0, 0.f);
        o1 = fmaxf(o1, 0.f);
        o2 = fmaxf(o2, 0.f);
        o3 = fmaxf(o3, 0.f);
      }
      Y[base + cg] = o0;
      Y[base + cg + 32] = o1;
      Y[base + cg + 64] = o2;
      Y[base + cg + 96] = o3;
    }
  }
}

// ---------------- head: feat[c] += sum_rows relu(X@W + b)[row][c] ----------------
__global__ __launch_bounds__(256) void head_sum_kernel(const float* __restrict__ X,
                                                       const float* __restrict__ W,
                                                       const float* __restrict__ b,
                                                       float* __restrict__ feat, int N) {
  __shared__ float Wl[32 * 128];
  __shared__ float Xl[64 * 33];
  __shared__ float colsum[128];
  int tid = threadIdx.x;
  int row0 = blockIdx.x * 64;
  int cg = tid & 31, rg = tid >> 5;
  float acc[8][4] = {};
  for (int kb = 0; kb < 4; ++kb) {
    __syncthreads();
    for (int i = tid; i < 4096; i += 256) Wl[i] = W[kb * 4096 + i];
    for (int i = tid; i < 2048; i += 256) {
      int r = i >> 5, k = i & 31;
      int gr = row0 + r;
      Xl[r * 33 + k] = (gr < N) ? X[(size_t)gr * 128 + kb * 32 + k] : 0.f;
    }
    __syncthreads();
    for (int k = 0; k < 32; ++k) {
      float w0 = Wl[k * 128 + cg];
      float w1 = Wl[k * 128 + cg + 32];
      float w2 = Wl[k * 128 + cg + 64];
      float w3 = Wl[k * 128 + cg + 96];
#pragma unroll
      for (int i = 0; i < 8; ++i) {
        float xv = Xl[(rg * 8 + i) * 33 + k];
        acc[i][0] = fmaf(xv, w0, acc[i][0]);
        acc[i][1] = fmaf(xv, w1, acc[i][1]);
        acc[i][2] = fmaf(xv, w2, acc[i][2]);
        acc[i][3] = fmaf(xv, w3, acc[i][3]);
      }
    }
  }
  if (tid < 128) colsum[tid] = 0.f;
  __syncthreads();
  float b0 = b[cg], b1 = b[cg + 32], b2 = b[cg + 64], b3 = b[cg + 96];
  float part[4] = {0.f, 0.f, 0.f, 0.f};
#pragma unroll
  for (int i = 0; i < 8; ++i) {
    int gr = row0 + rg * 8 + i;
    if (gr < N) {
      part[0] += fmaxf(acc[i][0] + b0, 0.f);
      part[1] += fmaxf(acc[i][1] + b1, 0.f);
      part[2] += fmaxf(acc[i][2] + b2, 0.f);
      part[3] += fmaxf(acc[i][3] + b3, 0.f);
    }
  }
  atomicAdd(&colsum[cg], part[0]);
  atomicAdd(&colsum[cg + 32], part[1]);
  atomicAdd(&colsum[cg + 64], part[2]);
  atomicAdd(&colsum[cg + 96], part[3]);
  __syncthreads();
  if (tid < 128) atomicAdd(&feat[tid], colsum[tid]);
}

__global__ void final_fc_kernel(const float* __restrict__ fa, const float* __restrict__ frs,
                                const float* __restrict__ frd, const float* __restrict__ Wfc,
                                const float* __restrict__ bfc, float* __restrict__ out) {
  __shared__ float pooled[128];
  int t = threadIdx.x;
  if (t < 128)
    pooled[t] = (fa[t] * (1.f / 100000.f) + frs[t] * (1.f / 20000.f) + frd[t] * (1.f / 50000.f)) *
                (1.f / 3.f);
  __syncthreads();
  if (t < 64) {
    float s = bfc[t];
    for (int c = 0; c < 128; ++c) s = fmaf(pooled[c], Wfc[c * 64 + t], s);
    out[t] = s;
  }
}

// ---------------- orchestration ----------------

extern "C" void kernel_launch(void* const* d_in, const int* in_sizes, int n_in,
                              void* d_out, int out_size, void* d_ws, size_t ws_size,
                              hipStream_t stream) {
  const int N_ACT = 100000, N_RS = 20000, N_RD = 50000;
  const int E_F = 1600000, E_RS = 800000, E_RD = 800000, E_HRD = 800000;

  const float* x_act = (const float*)d_in[0];
  const float* x_rs = (const float*)d_in[1];
  const float* x_rd = (const float*)d_in[2];
  const int* ef_src = (const int*)d_in[3];
  const int* ef_dst = (const int*)d_in[4];
  const int* ers_src = (const int*)d_in[5];
  const int* ers_dst = (const int*)d_in[6];
  const int* erd_src = (const int*)d_in[7];
  const int* erd_dst = (const int*)d_in[8];
  const int* ehrd_src = (const int*)d_in[9];
  const int* ehrd_dst = (const int*)d_in[10];
  const float* Wsrc = (const float*)d_in[11];
  const float* Wdst = (const float*)d_in[12];
  const float* att_src = (const float*)d_in[13];
  const float* att_dst = (const float*)d_in[14];
  const float* b_gat = (const float*)d_in[15];
  const float* W_ln = (const float*)d_in[16];
  const float* b_ln = (const float*)d_in[17];
  const float* W_fc = (const float*)d_in[18];
  const float* b_fc = (const float*)d_in[19];
  float* out = (float*)d_out;

  float* w = (float*)d_ws;
  float* xaA = w;  w += (size_t)N_ACT * 128;
  float* xaB = w;  w += (size_t)N_ACT * 128;
  float* xrsA = w; w += (size_t)N_RS * 128;
  float* xrsB = w; w += (size_t)N_RS * 128;
  float* xrdA = w; w += (size_t)N_RD * 128;
  float* xrdB = w; w += (size_t)N_RD * 128;
  float* agg = w;  w += (size_t)N_ACT * 128;
  float* af_s = w;   w += N_ACT;
  float* af_d = w;   w += N_ACT;
  float* ars_s = w;  w += N_ACT;
  float* ahrd_s = w; w += N_ACT;
  float* ard_s = w;  w += N_RD;
  float* ard_d = w;  w += N_RD;
  float* ahrd_d = w; w += N_RD;
  float* ars_d = w;  w += N_RS;
  float* vs = w;   w += 1024;
  float* vd = w;   w += 1024;
  float* feats = w; w += 384;
  int* ip = (int*)w;
  int* rowptr_f = ip;   ip += N_ACT + 1;
  int* rowptr_rs = ip;  ip += N_RS + 1;
  int* rowptr_rd = ip;  ip += N_RD + 1;
  int* rowptr_hrd = ip; ip += N_RD + 1;
  int* csr_f = ip;      ip += E_F;
  int* csr_rs = ip;     ip += E_RS;
  int* csr_rd = ip;     ip += E_RD;
  int* csr_hrd = ip;    ip += E_HRD;
  int* cnt = ip;        ip += N_ACT;
  int* part = ip;       ip += 1024;

  // ---- build CSR for the 4 graphs (edge lists are layer-invariant) ----
  struct G {
    const int* src; const int* dst; int nd; int ne; int* rowptr; int* csr;
  } graphs[4] = {
    {ef_src, ef_dst, N_ACT, E_F, rowptr_f, csr_f},
    {ers_src, ers_dst, N_RS, E_RS, rowptr_rs, csr_rs},
    {erd_src, erd_dst, N_RD, E_RD, rowptr_rd, csr_rd},
    {ehrd_src, ehrd_dst, N_RD, E_HRD, rowptr_hrd, csr_hrd},
  };
  for (int g = 0; g < 4; ++g) {
    const G& Gr = graphs[g];
    int nb = (Gr.nd + 1 + 255) / 256;
    fill_i_kernel<<<(Gr.nd + 255) / 256, 256, 0, stream>>>(cnt, 0, Gr.nd);
    hist_kernel<<<(Gr.ne + 255) / 256, 256, 0, stream>>>(Gr.dst, cnt, Gr.ne);
    partial_sum_kernel<<<nb, 256, 0, stream>>>(cnt, part, Gr.nd);
    scan_part_kernel<<<1, 64, 0, stream>>>(part, nb);
    scan_final_kernel<<<nb, 256, 0, stream>>>(cnt, part, Gr.rowptr, Gr.nd);
    fill_i_kernel<<<(Gr.nd + 255) / 256, 256, 0, stream>>>(cnt, 0, Gr.nd);
    scatter_kernel<<<(Gr.ne + 255) / 256, 256, 0, stream>>>(Gr.src, Gr.dst, Gr.rowptr, cnt,
                                                            Gr.csr, Gr.ne);
  }

  compute_v_kernel<<<8, 128, 0, stream>>>(Wsrc, att_src, vs);
  compute_v_kernel<<<8, 128, 0, stream>>>(Wdst, att_dst, vd);

  const float* xa = x_act;
  const float* xrs = x_rs;
  const float* xrd = x_rd;

  for (int L = 0; L < 2; ++L) {
    float* na = (L == 0) ? xaA : xaB;
    float* nrs = (L == 0) ? xrsA : xrsB;
    float* nrd = (L == 0) ? xrdA : xrdB;

    // ---- all alphas for this layer: one pass per node type ----
    matvecN_kernel<4><<<(N_ACT + 3) / 4, 256, 0, stream>>>(
        xa, vs + (0 + L) * 128, vd + (0 + L) * 128, vs + (2 + L) * 128, vs + (6 + L) * 128,
        af_s, af_d, ars_s, ahrd_s, N_ACT);
    matvecN_kernel<3><<<(N_RD + 3) / 4, 256, 0, stream>>>(
        xrd, vs + (4 + L) * 128, vd + (4 + L) * 128, vd + (6 + L) * 128, nullptr,
        ard_s, ard_d, ahrd_d, nullptr, N_RD);
    matvecN_kernel<1><<<(N_RS + 3) / 4, 256, 0, stream>>>(
        xrs, vd + (2 + L) * 128, nullptr, nullptr, nullptr,
        ars_d, nullptr, nullptr, nullptr, N_RS);

    struct Rel {
      const float* xs;
      int nd;
      const int* rowptr; const int* csr;
      const float* as; const float* ad;
      float* outb; int beta; int relu;
    } rels[4] = {
      {xa, N_ACT, rowptr_f, csr_f, af_s, af_d, na, 0, 1},
      {xa, N_RS, rowptr_rs, csr_rs, ars_s, ars_d, nrs, 0, 1},
      {xrd, N_RD, rowptr_rd, csr_rd, ard_s, ard_d, nrd, 0, 0},
      {xa, N_RD, rowptr_hrd, csr_hrd, ahrd_s, ahrd_d, nrd, 1, 1},
    };

    for (int r = 0; r < 4; ++r) {
      const Rel& R = rels[r];
      int g = r * 2 + L;
      gat_aggr_kernel<<<(R.nd + 3) / 4, 256, 0, stream>>>(R.rowptr, R.csr, R.as, R.ad, R.xs,
                                                          agg, R.nd);
      const float* bb = b_gat + g * 128;
      if (R.beta == 0 && R.relu == 1)
        gemm64_kernel<0, 1><<<(R.nd + 63) / 64, 256, 0, stream>>>(agg, Wsrc + (size_t)g * 16384,
                                                                  bb, R.outb, R.nd);
      else if (R.beta == 0 && R.relu == 0)
        gemm64_kernel<0, 0><<<(R.nd + 63) / 64, 256, 0, stream>>>(agg, Wsrc + (size_t)g * 16384,
                                                                  bb, R.outb, R.nd);
      else
        gemm64_kernel<1, 1><<<(R.nd + 63) / 64, 256, 0, stream>>>(agg, Wsrc + (size_t)g * 16384,
                                                                  bb, R.outb, R.nd);
    }

    xa = na; xrs = nrs; xrd = nrd;
  }

  fill_f_kernel<<<2, 256, 0, stream>>>(feats, 0.f, 384);
  head_sum_kernel<<<(N_ACT + 63) / 64, 256, 0, stream>>>(xa, W_ln, b_ln, feats, N_ACT);
  head_sum_kernel<<<(N_RS + 63) / 64, 256, 0, stream>>>(xrs, W_ln, b_ln, feats + 128, N_RS);
  head_sum_kernel<<<(N_RD + 63) / 64, 256, 0, stream>>>(xrd, W_ln, b_ln, feats + 256, N_RD);
  final_fc_kernel<<<1, 128, 0, stream>>>(feats, feats + 128, feats + 256, W_fc, b_fc, out);
}

// Round 5
// 1679.439 us; speedup vs baseline: 3.3242x; 1.0678x over previous
//
#include <hip/hip_runtime.h>
#include <cmath>

#define HID 128

// ---------------- utility kernels ----------------

__global__ void fill_f_kernel(float* p, float v, int n) {
  int i = blockIdx.x * 256 + threadIdx.x;
  if (i < n) p[i] = v;
}

__global__ void fill_i_kernel(int* p, int v, int n) {
  int i = blockIdx.x * 256 + threadIdx.x;
  if (i < n) p[i] = v;
}

// fp32 -> bf16 (RNE), 8 elements per thread
__global__ void f2bf_kernel(const float* __restrict__ in, unsigned short* __restrict__ out,
                            int n8) {
  int i = blockIdx.x * 256 + threadIdx.x;
  if (i >= n8) return;
  const float4* p4 = reinterpret_cast<const float4*>(in) + (size_t)i * 2;
  float4 v0 = p4[0], v1 = p4[1];
  float vv[8] = {v0.x, v0.y, v0.z, v0.w, v1.x, v1.y, v1.z, v1.w};
  unsigned int r[8];
#pragma unroll
  for (int j = 0; j < 8; ++j) {
    unsigned int b = __float_as_uint(vv[j]);
    r[j] = (b + 0x7fffu + ((b >> 16) & 1u)) >> 16;
  }
  uint4 o;
  o.x = r[0] | (r[1] << 16);
  o.y = r[2] | (r[3] << 16);
  o.z = r[4] | (r[5] << 16);
  o.w = r[6] | (r[7] << 16);
  reinterpret_cast<uint4*>(out)[i] = o;
}

// v[g][k] = sum_c W[g][k][c] * a[g][c]   (g = rel*2 + layer, 8 groups)
__global__ void compute_v_kernel(const float* __restrict__ W, const float* __restrict__ a,
                                 float* __restrict__ v) {
  int g = blockIdx.x, k = threadIdx.x;
  const float* Wg = W + g * 16384;
  const float* ag = a + g * 128;
  float s = 0.f;
  for (int c = 0; c < 128; ++c) s = fmaf(Wg[k * 128 + c], ag[c], s);
  v[g * 128 + k] = s;
}

// up to 4 dot products per row in ONE pass over X
template <int NV>
__global__ __launch_bounds__(256) void matvecN_kernel(
    const float* __restrict__ X, const float* __restrict__ v0, const float* __restrict__ v1,
    const float* __restrict__ v2, const float* __restrict__ v3, float* __restrict__ o0,
    float* __restrict__ o1, float* __restrict__ o2, float* __restrict__ o3, int N) {
  __shared__ float vl[NV][128];
  int tid = threadIdx.x;
  if (tid < 128) {
    vl[0][tid] = v0[tid];
    if (NV > 1) vl[1][tid] = v1[tid];
    if (NV > 2) vl[2][tid] = v2[tid];
    if (NV > 3) vl[3][tid] = v3[tid];
  }
  __syncthreads();
  int wave = tid >> 6, lane = tid & 63;
  int row = blockIdx.x * 4 + wave;
  if (row >= N) return;
  float x0 = X[(size_t)row * 128 + lane];
  float x1 = X[(size_t)row * 128 + 64 + lane];
  float a[NV];
#pragma unroll
  for (int j = 0; j < NV; ++j) a[j] = x0 * vl[j][lane] + x1 * vl[j][64 + lane];
#pragma unroll
  for (int j = 0; j < NV; ++j) {
    float s = a[j];
#pragma unroll
    for (int off = 32; off >= 1; off >>= 1) s += __shfl_down(s, off);
    a[j] = s;
  }
  if (lane == 0) {
    o0[row] = a[0];
    if (NV > 1) o1[row] = a[1];
    if (NV > 2) o2[row] = a[2];
    if (NV > 3) o3[row] = a[3];
  }
}

// ---------------- CSR build (counting sort by dst) ----------------

__global__ void hist_kernel(const int* __restrict__ dst, int* __restrict__ cnt, int E) {
  int e = blockIdx.x * 256 + threadIdx.x;
  if (e < E) atomicAdd(&cnt[dst[e]], 1);
}

__global__ void partial_sum_kernel(const int* __restrict__ cnt, int* __restrict__ part, int n) {
  __shared__ int tmp[256];
  int i = blockIdx.x * 256 + threadIdx.x;
  tmp[threadIdx.x] = (i < n) ? cnt[i] : 0;
  __syncthreads();
  for (int off = 128; off; off >>= 1) {
    if (threadIdx.x < off) tmp[threadIdx.x] += tmp[threadIdx.x + off];
    __syncthreads();
  }
  if (threadIdx.x == 0) part[blockIdx.x] = tmp[0];
}

__global__ void scan_part_kernel(int* part, int nb) {
  if (threadIdx.x == 0 && blockIdx.x == 0) {
    int run = 0;
    for (int b = 0; b < nb; ++b) {
      int t = part[b];
      part[b] = run;
      run += t;
    }
  }
}

__global__ void scan_final_kernel(const int* __restrict__ cnt, const int* __restrict__ part,
                                  int* __restrict__ rowptr, int n) {
  __shared__ int tmp[256];
  int tid = threadIdx.x;
  int i = blockIdx.x * 256 + tid;
  int v = (i < n) ? cnt[i] : 0;
  tmp[tid] = v;
  __syncthreads();
  for (int off = 1; off < 256; off <<= 1) {
    int t = (tid >= off) ? tmp[tid - off] : 0;
    __syncthreads();
    tmp[tid] += t;
    __syncthreads();
  }
  if (i <= n) rowptr[i] = part[blockIdx.x] + tmp[tid] - v;  // exclusive; i==n -> total E
}

__global__ void scatter_kernel(const int* __restrict__ src, const int* __restrict__ dst,
                               const int* __restrict__ rowptr, int* __restrict__ fill,
                               int* __restrict__ csr, int E) {
  int e = blockIdx.x * 256 + threadIdx.x;
  if (e >= E) return;
  int d = dst[e];
  int pos = rowptr[d] + atomicAdd(&fill[d], 1);
  csr[pos] = src[e];
}

// ---------------- GAT aggregation: one wave per dst, bf16 gather, 4 edges/iter ----------------
// agg[d] = sum_j softmax_j(leakyrelu(as[src_j]+ad[d])) * X[src_j]
__global__ __launch_bounds__(256) void gat_aggr_kernel(
    const int* __restrict__ rowptr, const int* __restrict__ csr, const float* __restrict__ as_,
    const float* __restrict__ ad_, const unsigned short* __restrict__ Xh,
    float* __restrict__ agg, int n_dst) {
  int wave = threadIdx.x >> 6, lane = threadIdx.x & 63;
  int g = lane >> 4, li = lane & 15;  // edge subgroup / column group (cols li*8..li*8+7)
  int d = blockIdx.x * 4 + wave;
  if (d >= n_dst) return;
  int beg = rowptr[d], end = rowptr[d + 1];
  float ad = ad_[d];
  float m = -INFINITY, z = 0.f;
  float a[8] = {};
  for (int c0 = beg; c0 < end; c0 += 64) {
    int j = c0 + lane;
    int s = 0;
    float e = -INFINITY;
    if (j < end) {
      s = csr[j];
      float t = as_[s] + ad;
      e = t > 0.f ? t : 0.2f * t;
    }
    float cm = e;
#pragma unroll
    for (int off = 32; off; off >>= 1) cm = fmaxf(cm, __shfl_xor(cm, off));
    float mn = fmaxf(m, cm);
    float p = (j < end) ? expf(e - mn) : 0.f;
    float ps = p;
#pragma unroll
    for (int off = 32; off; off >>= 1) ps += __shfl_xor(ps, off);
    float scale = expf(m - mn);  // first chunk: exp(-inf)=0, accs are 0 anyway
#pragma unroll
    for (int i = 0; i < 8; ++i) a[i] *= scale;
    z = z * scale + ps;
    m = mn;
    int cnt = min(64, end - c0);
    for (int k = 0; k < cnt; k += 4) {
      int idx = k + g;  // subgroup g handles edge k+g
      float wgt = __shfl(p, idx);
      int s2 = __shfl(s, idx);
      if (idx < cnt) {
        const uint4 xv = *reinterpret_cast<const uint4*>(Xh + (size_t)s2 * 128 + li * 8);
        float f0 = __uint_as_float(xv.x << 16);
        float f1 = __uint_as_float(xv.x & 0xFFFF0000u);
        float f2 = __uint_as_float(xv.y << 16);
        float f3 = __uint_as_float(xv.y & 0xFFFF0000u);
        float f4 = __uint_as_float(xv.z << 16);
        float f5 = __uint_as_float(xv.z & 0xFFFF0000u);
        float f6 = __uint_as_float(xv.w << 16);
        float f7 = __uint_as_float(xv.w & 0xFFFF0000u);
        a[0] = fmaf(wgt, f0, a[0]);
        a[1] = fmaf(wgt, f1, a[1]);
        a[2] = fmaf(wgt, f2, a[2]);
        a[3] = fmaf(wgt, f3, a[3]);
        a[4] = fmaf(wgt, f4, a[4]);
        a[5] = fmaf(wgt, f5, a[5]);
        a[6] = fmaf(wgt, f6, a[6]);
        a[7] = fmaf(wgt, f7, a[7]);
      }
    }
  }
  // combine the 4 subgroups (same columns within each li)
#pragma unroll
  for (int i = 0; i < 8; ++i) {
    a[i] += __shfl_xor(a[i], 32);
    a[i] += __shfl_xor(a[i], 16);
  }
  if (g == 0) {
    float inv = 1.f / fmaxf(z, 1e-16f);
    float4 r0, r1;
    r0.x = a[0] * inv; r0.y = a[1] * inv; r0.z = a[2] * inv; r0.w = a[3] * inv;
    r1.x = a[4] * inv; r1.y = a[5] * inv; r1.z = a[6] * inv; r1.w = a[7] * inv;
    *reinterpret_cast<float4*>(agg + (size_t)d * 128 + li * 8) = r0;
    *reinterpret_cast<float4*>(agg + (size_t)d * 128 + li * 8 + 4) = r1;
  }
}

// ---------------- GEMM: Y = [Y +] X@W + bias [, relu] ----------------
template <int BETA, int RELU>
__global__ __launch_bounds__(256) void gemm64_kernel(const float* __restrict__ X,
                                                     const float* __restrict__ W,
                                                     const float* __restrict__ bias,
                                                     float* __restrict__ Y, int N) {
  __shared__ float Wl[32 * 128];
  __shared__ float Xl[64 * 33];
  int tid = threadIdx.x;
  int row0 = blockIdx.x * 64;
  int cg = tid & 31, rg = tid >> 5;
  float acc[8][4] = {};
  for (int kb = 0; kb < 4; ++kb) {
    __syncthreads();
    for (int i = tid; i < 4096; i += 256) Wl[i] = W[kb * 4096 + i];
    for (int i = tid; i < 2048; i += 256) {
      int r = i >> 5, k = i & 31;
      int gr = row0 + r;
      Xl[r * 33 + k] = (gr < N) ? X[(size_t)gr * 128 + kb * 32 + k] : 0.f;
    }
    __syncthreads();
    for (int k = 0; k < 32; ++k) {
      float w0 = Wl[k * 128 + cg];
      float w1 = Wl[k * 128 + cg + 32];
      float w2 = Wl[k * 128 + cg + 64];
      float w3 = Wl[k * 128 + cg + 96];
#pragma unroll
      for (int i = 0; i < 8; ++i) {
        float xv = Xl[(rg * 8 + i) * 33 + k];
        acc[i][0] = fmaf(xv, w0, acc[i][0]);
        acc[i][1] = fmaf(xv, w1, acc[i][1]);
        acc[i][2] = fmaf(xv, w2, acc[i][2]);
        acc[i][3] = fmaf(xv, w3, acc[i][3]);
      }
    }
  }
  float b0 = bias[cg], b1 = bias[cg + 32], b2 = bias[cg + 64], b3 = bias[cg + 96];
#pragma unroll
  for (int i = 0; i < 8; ++i) {
    int gr = row0 + rg * 8 + i;
    if (gr < N) {
      size_t base = (size_t)gr * 128;
      float o0 = acc[i][0] + b0;
      float o1 = acc[i][1] + b1;
      float o2 = acc[i][2] + b2;
      float o3 = acc[i][3] + b3;
      if (BETA) {
        o0 += Y[base + cg];
        o1 += Y[base + cg + 32];
        o2 += Y[base + cg + 64];
        o3 += Y[base + cg + 96];
      }
      if (RELU) {
        o0 = fmaxf(o0, 0.f);
        o1 = fmaxf(o1, 0.f);
        o2 = fmaxf(o2, 0.f);
        o3 = fmaxf(o3, 0.f);
      }
      Y[base + cg] = o0;
      Y[base + cg + 32] = o1;
      Y[base + cg + 64] = o2;
      Y[base + cg + 96] = o3;
    }
  }
}

// ---------------- head: feat[c] += sum_rows relu(X@W + b)[row][c] ----------------
__global__ __launch_bounds__(256) void head_sum_kernel(const float* __restrict__ X,
                                                       const float* __restrict__ W,
                                                       const float* __restrict__ b,
                                                       float* __restrict__ feat, int N) {
  __shared__ float Wl[32 * 128];
  __shared__ float Xl[64 * 33];
  __shared__ float colsum[128];
  int tid = threadIdx.x;
  int row0 = blockIdx.x * 64;
  int cg = tid & 31, rg = tid >> 5;
  float acc[8][4] = {};
  for (int kb = 0; kb < 4; ++kb) {
    __syncthreads();
    for (int i = tid; i < 4096; i += 256) Wl[i] = W[kb * 4096 + i];
    for (int i = tid; i < 2048; i += 256) {
      int r = i >> 5, k = i & 31;
      int gr = row0 + r;
      Xl[r * 33 + k] = (gr < N) ? X[(size_t)gr * 128 + kb * 32 + k] : 0.f;
    }
    __syncthreads();
    for (int k = 0; k < 32; ++k) {
      float w0 = Wl[k * 128 + cg];
      float w1 = Wl[k * 128 + cg + 32];
      float w2 = Wl[k * 128 + cg + 64];
      float w3 = Wl[k * 128 + cg + 96];
#pragma unroll
      for (int i = 0; i < 8; ++i) {
        float xv = Xl[(rg * 8 + i) * 33 + k];
        acc[i][0] = fmaf(xv, w0, acc[i][0]);
        acc[i][1] = fmaf(xv, w1, acc[i][1]);
        acc[i][2] = fmaf(xv, w2, acc[i][2]);
        acc[i][3] = fmaf(xv, w3, acc[i][3]);
      }
    }
  }
  if (tid < 128) colsum[tid] = 0.f;
  __syncthreads();
  float b0 = b[cg], b1 = b[cg + 32], b2 = b[cg + 64], b3 = b[cg + 96];
  float part[4] = {0.f, 0.f, 0.f, 0.f};
#pragma unroll
  for (int i = 0; i < 8; ++i) {
    int gr = row0 + rg * 8 + i;
    if (gr < N) {
      part[0] += fmaxf(acc[i][0] + b0, 0.f);
      part[1] += fmaxf(acc[i][1] + b1, 0.f);
      part[2] += fmaxf(acc[i][2] + b2, 0.f);
      part[3] += fmaxf(acc[i][3] + b3, 0.f);
    }
  }
  atomicAdd(&colsum[cg], part[0]);
  atomicAdd(&colsum[cg + 32], part[1]);
  atomicAdd(&colsum[cg + 64], part[2]);
  atomicAdd(&colsum[cg + 96], part[3]);
  __syncthreads();
  if (tid < 128) atomicAdd(&feat[tid], colsum[tid]);
}

__global__ void final_fc_kernel(const float* __restrict__ fa, const float* __restrict__ frs,
                                const float* __restrict__ frd, const float* __restrict__ Wfc,
                                const float* __restrict__ bfc, float* __restrict__ out) {
  __shared__ float pooled[128];
  int t = threadIdx.x;
  if (t < 128)
    pooled[t] = (fa[t] * (1.f / 100000.f) + frs[t] * (1.f / 20000.f) + frd[t] * (1.f / 50000.f)) *
                (1.f / 3.f);
  __syncthreads();
  if (t < 64) {
    float s = bfc[t];
    for (int c = 0; c < 128; ++c) s = fmaf(pooled[c], Wfc[c * 64 + t], s);
    out[t] = s;
  }
}

// ---------------- orchestration ----------------

extern "C" void kernel_launch(void* const* d_in, const int* in_sizes, int n_in,
                              void* d_out, int out_size, void* d_ws, size_t ws_size,
                              hipStream_t stream) {
  const int N_ACT = 100000, N_RS = 20000, N_RD = 50000;
  const int E_F = 1600000, E_RS = 800000, E_RD = 800000, E_HRD = 800000;

  const float* x_act = (const float*)d_in[0];
  const float* x_rs = (const float*)d_in[1];
  const float* x_rd = (const float*)d_in[2];
  const int* ef_src = (const int*)d_in[3];
  const int* ef_dst = (const int*)d_in[4];
  const int* ers_src = (const int*)d_in[5];
  const int* ers_dst = (const int*)d_in[6];
  const int* erd_src = (const int*)d_in[7];
  const int* erd_dst = (const int*)d_in[8];
  const int* ehrd_src = (const int*)d_in[9];
  const int* ehrd_dst = (const int*)d_in[10];
  const float* Wsrc = (const float*)d_in[11];
  const float* Wdst = (const float*)d_in[12];
  const float* att_src = (const float*)d_in[13];
  const float* att_dst = (const float*)d_in[14];
  const float* b_gat = (const float*)d_in[15];
  const float* W_ln = (const float*)d_in[16];
  const float* b_ln = (const float*)d_in[17];
  const float* W_fc = (const float*)d_in[18];
  const float* b_fc = (const float*)d_in[19];
  float* out = (float*)d_out;

  // ---- workspace layout (single-buffered state; ~196 MB total) ----
  // Within a layer, fp32 state is read ONLY at layer start (mirror + alphas);
  // aggregation uses the bf16 mirror and GEMM reads `agg`, so layer outputs
  // may safely overwrite layer inputs.
  float* w = (float*)d_ws;
  float* xa_buf = w;  w += (size_t)N_ACT * 128;
  float* xrs_buf = w; w += (size_t)N_RS * 128;
  float* xrd_buf = w; w += (size_t)N_RD * 128;
  float* agg = w;     w += (size_t)N_ACT * 128;
  float* af_s = w;   w += N_ACT;
  float* af_d = w;   w += N_ACT;
  float* ars_s = w;  w += N_ACT;
  float* ahrd_s = w; w += N_ACT;
  float* ard_s = w;  w += N_RD;
  float* ard_d = w;  w += N_RD;
  float* ahrd_d = w; w += N_RD;
  float* ars_d = w;  w += N_RS;
  float* vs = w;    w += 1024;
  float* vd = w;    w += 1024;
  float* feats = w; w += 384;
  unsigned short* xah = (unsigned short*)w;  w += (size_t)N_ACT * 64;  // bf16 mirror
  unsigned short* xrdh = (unsigned short*)w; w += (size_t)N_RD * 64;
  int* ip = (int*)w;
  int* rowptr_f = ip;   ip += N_ACT + 1;
  int* rowptr_rs = ip;  ip += N_RS + 1;
  int* rowptr_rd = ip;  ip += N_RD + 1;
  int* rowptr_hrd = ip; ip += N_RD + 1;
  int* csr_f = ip;      ip += E_F;
  int* csr_rs = ip;     ip += E_RS;
  int* csr_rd = ip;     ip += E_RD;
  int* csr_hrd = ip;    ip += E_HRD;
  int* cnt = ip;        ip += N_ACT;
  int* part = ip;       ip += 1024;

  // ---- build CSR for the 4 graphs (edge lists are layer-invariant) ----
  struct G {
    const int* src; const int* dst; int nd; int ne; int* rowptr; int* csr;
  } graphs[4] = {
    {ef_src, ef_dst, N_ACT, E_F, rowptr_f, csr_f},
    {ers_src, ers_dst, N_RS, E_RS, rowptr_rs, csr_rs},
    {erd_src, erd_dst, N_RD, E_RD, rowptr_rd, csr_rd},
    {ehrd_src, ehrd_dst, N_RD, E_HRD, rowptr_hrd, csr_hrd},
  };
  for (int g = 0; g < 4; ++g) {
    const G& Gr = graphs[g];
    int nb = (Gr.nd + 1 + 255) / 256;
    fill_i_kernel<<<(Gr.nd + 255) / 256, 256, 0, stream>>>(cnt, 0, Gr.nd);
    hist_kernel<<<(Gr.ne + 255) / 256, 256, 0, stream>>>(Gr.dst, cnt, Gr.ne);
    partial_sum_kernel<<<nb, 256, 0, stream>>>(cnt, part, Gr.nd);
    scan_part_kernel<<<1, 64, 0, stream>>>(part, nb);
    scan_final_kernel<<<nb, 256, 0, stream>>>(cnt, part, Gr.rowptr, Gr.nd);
    fill_i_kernel<<<(Gr.nd + 255) / 256, 256, 0, stream>>>(cnt, 0, Gr.nd);
    scatter_kernel<<<(Gr.ne + 255) / 256, 256, 0, stream>>>(Gr.src, Gr.dst, Gr.rowptr, cnt,
                                                            Gr.csr, Gr.ne);
  }

  compute_v_kernel<<<8, 128, 0, stream>>>(Wsrc, att_src, vs);
  compute_v_kernel<<<8, 128, 0, stream>>>(Wdst, att_dst, vd);

  const float* xa = x_act;
  const float* xrs = x_rs;
  const float* xrd = x_rd;

  for (int L = 0; L < 2; ++L) {
    float* na = xa_buf;
    float* nrs = xrs_buf;
    float* nrd = xrd_buf;

    // ---- bf16 mirrors of the gather sources for this layer ----
    f2bf_kernel<<<(N_ACT * 16 + 255) / 256, 256, 0, stream>>>(xa, xah, N_ACT * 16);
    f2bf_kernel<<<(N_RD * 16 + 255) / 256, 256, 0, stream>>>(xrd, xrdh, N_RD * 16);

    // ---- all alphas for this layer: one pass per node type ----
    matvecN_kernel<4><<<(N_ACT + 3) / 4, 256, 0, stream>>>(
        xa, vs + (0 + L) * 128, vd + (0 + L) * 128, vs + (2 + L) * 128, vs + (6 + L) * 128,
        af_s, af_d, ars_s, ahrd_s, N_ACT);
    matvecN_kernel<3><<<(N_RD + 3) / 4, 256, 0, stream>>>(
        xrd, vs + (4 + L) * 128, vd + (4 + L) * 128, vd + (6 + L) * 128, nullptr,
        ard_s, ard_d, ahrd_d, nullptr, N_RD);
    matvecN_kernel<1><<<(N_RS + 3) / 4, 256, 0, stream>>>(
        xrs, vd + (2 + L) * 128, nullptr, nullptr, nullptr,
        ars_d, nullptr, nullptr, nullptr, N_RS);

    // fp32 state (xa/xrs/xrd) is now dead for this layer; outputs may overwrite it.
    struct Rel {
      const unsigned short* xsh;
      int nd;
      const int* rowptr; const int* csr;
      const float* as; const float* ad;
      float* outb; int beta; int relu;
    } rels[4] = {
      {xah, N_ACT, rowptr_f, csr_f, af_s, af_d, na, 0, 1},
      {xah, N_RS, rowptr_rs, csr_rs, ars_s, ars_d, nrs, 0, 1},
      {xrdh, N_RD, rowptr_rd, csr_rd, ard_s, ard_d, nrd, 0, 0},
      {xah, N_RD, rowptr_hrd, csr_hrd, ahrd_s, ahrd_d, nrd, 1, 1},
    };

    for (int r = 0; r < 4; ++r) {
      const Rel& R = rels[r];
      int g = r * 2 + L;
      gat_aggr_kernel<<<(R.nd + 3) / 4, 256, 0, stream>>>(R.rowptr, R.csr, R.as, R.ad, R.xsh,
                                                          agg, R.nd);
      const float* bb = b_gat + g * 128;
      if (R.beta == 0 && R.relu == 1)
        gemm64_kernel<0, 1><<<(R.nd + 63) / 64, 256, 0, stream>>>(agg, Wsrc + (size_t)g * 16384,
                                                                  bb, R.outb, R.nd);
      else if (R.beta == 0 && R.relu == 0)
        gemm64_kernel<0, 0><<<(R.nd + 63) / 64, 256, 0, stream>>>(agg, Wsrc + (size_t)g * 16384,
                                                                  bb, R.outb, R.nd);
      else
        gemm64_kernel<1, 1><<<(R.nd + 63) / 64, 256, 0, stream>>>(agg, Wsrc + (size_t)g * 16384,
                                                                  bb, R.outb, R.nd);
    }

    xa = xa_buf; xrs = xrs_buf; xrd = xrd_buf;
  }

  fill_f_kernel<<<2, 256, 0, stream>>>(feats, 0.f, 384);
  head_sum_kernel<<<(N_ACT + 63) / 64, 256, 0, stream>>>(xa, W_ln, b_ln, feats, N_ACT);
  head_sum_kernel<<<(N_RS + 63) / 64, 256, 0, stream>>>(xrs, W_ln, b_ln, feats + 128, N_RS);
  head_sum_kernel<<<(N_RD + 63) / 64, 256, 0, stream>>>(xrd, W_ln, b_ln, feats + 256, N_RD);
  final_fc_kernel<<<1, 128, 0, stream>>>(feats, feats + 128, feats + 256, W_fc, b_fc, out);
}

// Round 6
// 1268.090 us; speedup vs baseline: 4.4025x; 1.3244x over previous
//
#include <hip/hip_runtime.h>
#include <cmath>

#define HID 128

typedef __attribute__((ext_vector_type(8))) short bf16x8;
typedef __attribute__((ext_vector_type(4))) float f32x4;

__device__ inline unsigned short f2bf_rne(float f) {
  unsigned int b = __float_as_uint(f);
  return (unsigned short)((b + 0x7fffu + ((b >> 16) & 1u)) >> 16);
}
__device__ inline float bf2f(unsigned int u) { return __uint_as_float(u << 16); }

// ---------------- utility kernels ----------------

__global__ void fill_f_kernel(float* p, float v, int n) {
  int i = blockIdx.x * 256 + threadIdx.x;
  if (i < n) p[i] = v;
}

__global__ void fill_i_kernel(int* p, int v, int n) {
  int i = blockIdx.x * 256 + threadIdx.x;
  if (i < n) p[i] = v;
}

// fp32 -> bf16 (RNE), 8 elements per thread
__global__ void f2bf_kernel(const float* __restrict__ in, unsigned short* __restrict__ out,
                            int n8) {
  int i = blockIdx.x * 256 + threadIdx.x;
  if (i >= n8) return;
  const float4* p4 = reinterpret_cast<const float4*>(in) + (size_t)i * 2;
  float4 v0 = p4[0], v1 = p4[1];
  float vv[8] = {v0.x, v0.y, v0.z, v0.w, v1.x, v1.y, v1.z, v1.w};
  unsigned int r[8];
#pragma unroll
  for (int j = 0; j < 8; ++j) r[j] = f2bf_rne(vv[j]);
  uint4 o;
  o.x = r[0] | (r[1] << 16);
  o.y = r[2] | (r[3] << 16);
  o.z = r[4] | (r[5] << 16);
  o.w = r[6] | (r[7] << 16);
  reinterpret_cast<uint4*>(out)[i] = o;
}

// pack one 128x128 fp32 W (row-major [k][col]) into MFMA B-fragment order, bf16.
// o = (((half*4+ct)*4+kk)*64 + lane)*8 + j ; k = kk*32 + (lane>>4)*8 + j ; col = half*64+ct*16+(lane&15)
__global__ void pack_w_kernel(const float* __restrict__ W, unsigned short* __restrict__ Wp) {
  int o = blockIdx.x * 256 + threadIdx.x;
  if (o >= 16384) return;
  int j = o & 7;
  int lane = (o >> 3) & 63;
  int kk = (o >> 9) & 3;
  int ct = (o >> 11) & 3;
  int half = (o >> 13) & 1;
  int k = kk * 32 + ((lane >> 4) * 8) + j;
  int col = half * 64 + ct * 16 + (lane & 15);
  Wp[o] = f2bf_rne(W[k * 128 + col]);
}

// v[g][k] = sum_c W[g][k][c] * a[g][c]   (g = rel*2 + layer, 8 groups)
__global__ void compute_v_kernel(const float* __restrict__ W, const float* __restrict__ a,
                                 float* __restrict__ v) {
  int g = blockIdx.x, k = threadIdx.x;
  const float* Wg = W + g * 16384;
  const float* ag = a + g * 128;
  float s = 0.f;
  for (int c = 0; c < 128; ++c) s = fmaf(Wg[k * 128 + c], ag[c], s);
  v[g * 128 + k] = s;
}

// up to 4 dot products per row in ONE pass over bf16 X
template <int NV>
__global__ __launch_bounds__(256) void matvecN_kernel(
    const unsigned short* __restrict__ X, const float* __restrict__ v0,
    const float* __restrict__ v1, const float* __restrict__ v2, const float* __restrict__ v3,
    float* __restrict__ o0, float* __restrict__ o1, float* __restrict__ o2,
    float* __restrict__ o3, int N) {
  __shared__ float vl[NV][128];
  int tid = threadIdx.x;
  if (tid < 128) {
    vl[0][tid] = v0[tid];
    if (NV > 1) vl[1][tid] = v1[tid];
    if (NV > 2) vl[2][tid] = v2[tid];
    if (NV > 3) vl[3][tid] = v3[tid];
  }
  __syncthreads();
  int wave = tid >> 6, lane = tid & 63;
  int row = blockIdx.x * 4 + wave;
  if (row >= N) return;
  unsigned int u = *reinterpret_cast<const unsigned int*>(X + (size_t)row * 128 + lane * 2);
  float x0 = bf2f(u & 0xffffu), x1 = bf2f(u >> 16);
  float a[NV];
#pragma unroll
  for (int j = 0; j < NV; ++j) a[j] = x0 * vl[j][lane * 2] + x1 * vl[j][lane * 2 + 1];
#pragma unroll
  for (int j = 0; j < NV; ++j) {
    float s = a[j];
#pragma unroll
    for (int off = 32; off >= 1; off >>= 1) s += __shfl_down(s, off);
    a[j] = s;
  }
  if (lane == 0) {
    o0[row] = a[0];
    if (NV > 1) o1[row] = a[1];
    if (NV > 2) o2[row] = a[2];
    if (NV > 3) o3[row] = a[3];
  }
}

// ---------------- CSR build (counting sort by dst) ----------------

__global__ void hist_kernel(const int* __restrict__ dst, int* __restrict__ cnt, int E) {
  int e = blockIdx.x * 256 + threadIdx.x;
  if (e < E) atomicAdd(&cnt[dst[e]], 1);
}

__global__ void partial_sum_kernel(const int* __restrict__ cnt, int* __restrict__ part, int n) {
  __shared__ int tmp[256];
  int i = blockIdx.x * 256 + threadIdx.x;
  tmp[threadIdx.x] = (i < n) ? cnt[i] : 0;
  __syncthreads();
  for (int off = 128; off; off >>= 1) {
    if (threadIdx.x < off) tmp[threadIdx.x] += tmp[threadIdx.x + off];
    __syncthreads();
  }
  if (threadIdx.x == 0) part[blockIdx.x] = tmp[0];
}

__global__ void scan_part_kernel(int* part, int nb) {
  if (threadIdx.x == 0 && blockIdx.x == 0) {
    int run = 0;
    for (int b = 0; b < nb; ++b) {
      int t = part[b];
      part[b] = run;
      run += t;
    }
  }
}

__global__ void scan_final_kernel(const int* __restrict__ cnt, const int* __restrict__ part,
                                  int* __restrict__ rowptr, int n) {
  __shared__ int tmp[256];
  int tid = threadIdx.x;
  int i = blockIdx.x * 256 + tid;
  int v = (i < n) ? cnt[i] : 0;
  tmp[tid] = v;
  __syncthreads();
  for (int off = 1; off < 256; off <<= 1) {
    int t = (tid >= off) ? tmp[tid - off] : 0;
    __syncthreads();
    tmp[tid] += t;
    __syncthreads();
  }
  if (i <= n) rowptr[i] = part[blockIdx.x] + tmp[tid] - v;  // exclusive; i==n -> total E
}

__global__ void scatter_kernel(const int* __restrict__ src, const int* __restrict__ dst,
                               const int* __restrict__ rowptr, int* __restrict__ fill,
                               int* __restrict__ csr, int E) {
  int e = blockIdx.x * 256 + threadIdx.x;
  if (e >= E) return;
  int d = dst[e];
  int pos = rowptr[d] + atomicAdd(&fill[d], 1);
  csr[pos] = src[e];
}

// ---------------- GAT aggregation: one wave per dst, bf16 gather, 4 edges/iter ----------------
// aggh[d] = bf16( sum_j softmax_j(leakyrelu(as[src_j]+ad[d])) * X[src_j] )
__global__ __launch_bounds__(256) void gat_aggr_kernel(
    const int* __restrict__ rowptr, const int* __restrict__ csr, const float* __restrict__ as_,
    const float* __restrict__ ad_, const unsigned short* __restrict__ Xh,
    unsigned short* __restrict__ aggh, int n_dst) {
  int wave = threadIdx.x >> 6, lane = threadIdx.x & 63;
  int g = lane >> 4, li = lane & 15;  // edge subgroup / column group (cols li*8..li*8+7)
  int d = blockIdx.x * 4 + wave;
  if (d >= n_dst) return;
  int beg = rowptr[d], end = rowptr[d + 1];
  float ad = ad_[d];
  float m = -INFINITY, z = 0.f;
  float a[8] = {};
  for (int c0 = beg; c0 < end; c0 += 64) {
    int j = c0 + lane;
    int s = 0;
    float e = -INFINITY;
    if (j < end) {
      s = csr[j];
      float t = as_[s] + ad;
      e = t > 0.f ? t : 0.2f * t;
    }
    float cm = e;
#pragma unroll
    for (int off = 32; off; off >>= 1) cm = fmaxf(cm, __shfl_xor(cm, off));
    float mn = fmaxf(m, cm);
    float p = (j < end) ? expf(e - mn) : 0.f;
    float ps = p;
#pragma unroll
    for (int off = 32; off; off >>= 1) ps += __shfl_xor(ps, off);
    float scale = expf(m - mn);  // first chunk: exp(-inf)=0, accs are 0 anyway
#pragma unroll
    for (int i = 0; i < 8; ++i) a[i] *= scale;
    z = z * scale + ps;
    m = mn;
    int cnt = min(64, end - c0);
    for (int k = 0; k < cnt; k += 4) {
      int idx = k + g;  // subgroup g handles edge k+g
      float wgt = __shfl(p, idx);
      int s2 = __shfl(s, idx);
      if (idx < cnt) {
        const uint4 xv = *reinterpret_cast<const uint4*>(Xh + (size_t)s2 * 128 + li * 8);
        a[0] = fmaf(wgt, bf2f(xv.x & 0xffffu), a[0]);
        a[1] = fmaf(wgt, bf2f(xv.x >> 16), a[1]);
        a[2] = fmaf(wgt, bf2f(xv.y & 0xffffu), a[2]);
        a[3] = fmaf(wgt, bf2f(xv.y >> 16), a[3]);
        a[4] = fmaf(wgt, bf2f(xv.z & 0xffffu), a[4]);
        a[5] = fmaf(wgt, bf2f(xv.z >> 16), a[5]);
        a[6] = fmaf(wgt, bf2f(xv.w & 0xffffu), a[6]);
        a[7] = fmaf(wgt, bf2f(xv.w >> 16), a[7]);
      }
    }
  }
#pragma unroll
  for (int i = 0; i < 8; ++i) {
    a[i] += __shfl_xor(a[i], 32);
    a[i] += __shfl_xor(a[i], 16);
  }
  if (g == 0) {
    float inv = 1.f / fmaxf(z, 1e-16f);
    uint4 o;
    o.x = (unsigned)f2bf_rne(a[0] * inv) | ((unsigned)f2bf_rne(a[1] * inv) << 16);
    o.y = (unsigned)f2bf_rne(a[2] * inv) | ((unsigned)f2bf_rne(a[3] * inv) << 16);
    o.z = (unsigned)f2bf_rne(a[4] * inv) | ((unsigned)f2bf_rne(a[5] * inv) << 16);
    o.w = (unsigned)f2bf_rne(a[6] * inv) | ((unsigned)f2bf_rne(a[7] * inv) << 16);
    *reinterpret_cast<uint4*>(aggh + (size_t)d * 128 + li * 8) = o;
  }
}

// ---------------- MFMA GEMM: out = [add +] X@W + bias [, relu] ----------------
// X: bf16 [N][128]; Wp: packed bf16 fragments; block = 4 waves x 32 rows = 128 rows,
// 64 cols (blockIdx.y half). B held entirely in registers; no LDS, no barriers.
template <int BETA, int RELU, int OUT32>
__global__ __launch_bounds__(256) void gemm_mfma_kernel(
    const unsigned short* __restrict__ X, const unsigned short* __restrict__ Wp,
    const float* __restrict__ bias, const float* __restrict__ add,
    unsigned short* __restrict__ Yh, float* __restrict__ Yf, int N) {
  int wid = threadIdx.x >> 6, lane = threadIdx.x & 63;
  int half = blockIdx.y;
  int r0 = blockIdx.x * 128 + wid * 32;
  int lr = lane & 15, gk = lane >> 4;
  bf16x8 b[4][4];
#pragma unroll
  for (int ct = 0; ct < 4; ++ct)
#pragma unroll
    for (int kk = 0; kk < 4; ++kk)
      b[ct][kk] = *reinterpret_cast<const bf16x8*>(Wp + ((((half * 4 + ct) * 4 + kk) * 64 + lane) << 3));
  f32x4 acc[2][4];
#pragma unroll
  for (int rt = 0; rt < 2; ++rt)
#pragma unroll
    for (int ct = 0; ct < 4; ++ct) acc[rt][ct] = (f32x4){0.f, 0.f, 0.f, 0.f};
  int row0 = r0 + lr, row1 = r0 + 16 + lr;
#pragma unroll
  for (int kk = 0; kk < 4; ++kk) {
    bf16x8 a0 = {}, a1 = {};
    if (row0 < N) a0 = *reinterpret_cast<const bf16x8*>(X + (size_t)row0 * 128 + kk * 32 + gk * 8);
    if (row1 < N) a1 = *reinterpret_cast<const bf16x8*>(X + (size_t)row1 * 128 + kk * 32 + gk * 8);
#pragma unroll
    for (int ct = 0; ct < 4; ++ct) {
      acc[0][ct] = __builtin_amdgcn_mfma_f32_16x16x32_bf16(a0, b[ct][kk], acc[0][ct], 0, 0, 0);
      acc[1][ct] = __builtin_amdgcn_mfma_f32_16x16x32_bf16(a1, b[ct][kk], acc[1][ct], 0, 0, 0);
    }
  }
#pragma unroll
  for (int rt = 0; rt < 2; ++rt)
#pragma unroll
    for (int ct = 0; ct < 4; ++ct) {
      int col = half * 64 + ct * 16 + lr;
      float bcol = bias[col];
#pragma unroll
      for (int reg = 0; reg < 4; ++reg) {
        int row = r0 + rt * 16 + gk * 4 + reg;
        if (row < N) {
          float o = acc[rt][ct][reg] + bcol;
          if (BETA) o += add[(size_t)row * 128 + col];
          if (RELU) o = fmaxf(o, 0.f);
          if (OUT32) Yf[(size_t)row * 128 + col] = o;
          else       Yh[(size_t)row * 128 + col] = f2bf_rne(o);
        }
      }
    }
}

// ---------------- MFMA head: feat[c] += sum_rows relu(X@W + b)[row][c] ----------------
// 512 rows per block (4 chunks of 128), 64 cols per blockIdx.y half.
__global__ __launch_bounds__(256) void head_mfma_kernel(
    const unsigned short* __restrict__ X, const unsigned short* __restrict__ Wp,
    const float* __restrict__ bias, float* __restrict__ feat, int N) {
  __shared__ float cs[64];
  int wid = threadIdx.x >> 6, lane = threadIdx.x & 63;
  int half = blockIdx.y;
  int lr = lane & 15, gk = lane >> 4;
  if (threadIdx.x < 64) cs[threadIdx.x] = 0.f;
  __syncthreads();
  bf16x8 b[4][4];
#pragma unroll
  for (int ct = 0; ct < 4; ++ct)
#pragma unroll
    for (int kk = 0; kk < 4; ++kk)
      b[ct][kk] = *reinterpret_cast<const bf16x8*>(Wp + ((((half * 4 + ct) * 4 + kk) * 64 + lane) << 3));
  float colsum[4] = {0.f, 0.f, 0.f, 0.f};
  for (int c = 0; c < 4; ++c) {
    int r0 = blockIdx.x * 512 + c * 128 + wid * 32;
    if (r0 >= N) break;
    f32x4 acc[2][4];
#pragma unroll
    for (int rt = 0; rt < 2; ++rt)
#pragma unroll
      for (int ct = 0; ct < 4; ++ct) acc[rt][ct] = (f32x4){0.f, 0.f, 0.f, 0.f};
    int row0 = r0 + lr, row1 = r0 + 16 + lr;
#pragma unroll
    for (int kk = 0; kk < 4; ++kk) {
      bf16x8 a0 = {}, a1 = {};
      if (row0 < N) a0 = *reinterpret_cast<const bf16x8*>(X + (size_t)row0 * 128 + kk * 32 + gk * 8);
      if (row1 < N) a1 = *reinterpret_cast<const bf16x8*>(X + (size_t)row1 * 128 + kk * 32 + gk * 8);
#pragma unroll
      for (int ct = 0; ct < 4; ++ct) {
        acc[0][ct] = __builtin_amdgcn_mfma_f32_16x16x32_bf16(a0, b[ct][kk], acc[0][ct], 0, 0, 0);
        acc[1][ct] = __builtin_amdgcn_mfma_f32_16x16x32_bf16(a1, b[ct][kk], acc[1][ct], 0, 0, 0);
      }
    }
#pragma unroll
    for (int rt = 0; rt < 2; ++rt)
#pragma unroll
      for (int ct = 0; ct < 4; ++ct) {
        float bcol = bias[half * 64 + ct * 16 + lr];
#pragma unroll
        for (int reg = 0; reg < 4; ++reg) {
          int row = r0 + rt * 16 + gk * 4 + reg;
          if (row < N) colsum[ct] += fmaxf(acc[rt][ct][reg] + bcol, 0.f);
        }
      }
  }
#pragma unroll
  for (int ct = 0; ct < 4; ++ct) {
    float v = colsum[ct];
    v += __shfl_xor(v, 16);
    v += __shfl_xor(v, 32);
    if (gk == 0) atomicAdd(&cs[ct * 16 + lr], v);
  }
  __syncthreads();
  if (threadIdx.x < 64) atomicAdd(&feat[half * 64 + threadIdx.x], cs[threadIdx.x]);
}

__global__ void final_fc_kernel(const float* __restrict__ fa, const float* __restrict__ frs,
                                const float* __restrict__ frd, const float* __restrict__ Wfc,
                                const float* __restrict__ bfc, float* __restrict__ out) {
  __shared__ float pooled[128];
  int t = threadIdx.x;
  if (t < 128)
    pooled[t] = (fa[t] * (1.f / 100000.f) + frs[t] * (1.f / 20000.f) + frd[t] * (1.f / 50000.f)) *
                (1.f / 3.f);
  __syncthreads();
  if (t < 64) {
    float s = bfc[t];
    for (int c = 0; c < 128; ++c) s = fmaf(pooled[c], Wfc[c * 64 + t], s);
    out[t] = s;
  }
}

// ---------------- orchestration ----------------

extern "C" void kernel_launch(void* const* d_in, const int* in_sizes, int n_in,
                              void* d_out, int out_size, void* d_ws, size_t ws_size,
                              hipStream_t stream) {
  const int N_ACT = 100000, N_RS = 20000, N_RD = 50000;
  const int E_F = 1600000, E_RS = 800000, E_RD = 800000, E_HRD = 800000;

  const float* x_act = (const float*)d_in[0];
  const float* x_rs = (const float*)d_in[1];
  const float* x_rd = (const float*)d_in[2];
  const int* ef_src = (const int*)d_in[3];
  const int* ef_dst = (const int*)d_in[4];
  const int* ers_src = (const int*)d_in[5];
  const int* ers_dst = (const int*)d_in[6];
  const int* erd_src = (const int*)d_in[7];
  const int* erd_dst = (const int*)d_in[8];
  const int* ehrd_src = (const int*)d_in[9];
  const int* ehrd_dst = (const int*)d_in[10];
  const float* Wsrc = (const float*)d_in[11];
  const float* Wdst = (const float*)d_in[12];
  const float* att_src = (const float*)d_in[13];
  const float* att_dst = (const float*)d_in[14];
  const float* b_gat = (const float*)d_in[15];
  const float* W_ln = (const float*)d_in[16];
  const float* b_ln = (const float*)d_in[17];
  const float* W_fc = (const float*)d_in[18];
  const float* b_fc = (const float*)d_in[19];
  float* out = (float*)d_out;

  // ---- workspace layout (~155 MB) ----
  float* w = (float*)d_ws;
  float* tmp = w;   w += (size_t)N_RD * 128;  // fp32 partial for the rd beta path
  float* af_s = w;   w += N_ACT;
  float* af_d = w;   w += N_ACT;
  float* ars_s = w;  w += N_ACT;
  float* ahrd_s = w; w += N_ACT;
  float* ard_s = w;  w += N_RD;
  float* ard_d = w;  w += N_RD;
  float* ahrd_d = w; w += N_RD;
  float* ars_d = w;  w += N_RS;
  float* vs = w;    w += 1024;
  float* vd = w;    w += 1024;
  float* feats = w; w += 384;
  unsigned short* xa0 = (unsigned short*)w;   w += (size_t)N_ACT * 64;  // bf16 state (dbl-buffered)
  unsigned short* xa1 = (unsigned short*)w;   w += (size_t)N_ACT * 64;
  unsigned short* xrd0 = (unsigned short*)w;  w += (size_t)N_RD * 64;
  unsigned short* xrd1 = (unsigned short*)w;  w += (size_t)N_RD * 64;
  unsigned short* xrs_b = (unsigned short*)w; w += (size_t)N_RS * 64;
  unsigned short* aggh = (unsigned short*)w;  w += (size_t)N_ACT * 64;
  unsigned short* wpack = (unsigned short*)w; w += (9 * 16384) / 2;  // 8 GAT + W_ln, bf16 frags
  int* ip = (int*)w;
  int* rowptr_f = ip;   ip += N_ACT + 1;
  int* rowptr_rs = ip;  ip += N_RS + 1;
  int* rowptr_rd = ip;  ip += N_RD + 1;
  int* rowptr_hrd = ip; ip += N_RD + 1;
  int* csr_f = ip;      ip += E_F;
  int* csr_rs = ip;     ip += E_RS;
  int* csr_rd = ip;     ip += E_RD;
  int* csr_hrd = ip;    ip += E_HRD;
  int* cnt = ip;        ip += N_ACT;
  int* part = ip;       ip += 1024;

  // ---- build CSR for the 4 graphs (edge lists are layer-invariant) ----
  struct G {
    const int* src; const int* dst; int nd; int ne; int* rowptr; int* csr;
  } graphs[4] = {
    {ef_src, ef_dst, N_ACT, E_F, rowptr_f, csr_f},
    {ers_src, ers_dst, N_RS, E_RS, rowptr_rs, csr_rs},
    {erd_src, erd_dst, N_RD, E_RD, rowptr_rd, csr_rd},
    {ehrd_src, ehrd_dst, N_RD, E_HRD, rowptr_hrd, csr_hrd},
  };
  for (int g = 0; g < 4; ++g) {
    const G& Gr = graphs[g];
    int nb = (Gr.nd + 1 + 255) / 256;
    fill_i_kernel<<<(Gr.nd + 255) / 256, 256, 0, stream>>>(cnt, 0, Gr.nd);
    hist_kernel<<<(Gr.ne + 255) / 256, 256, 0, stream>>>(Gr.dst, cnt, Gr.ne);
    partial_sum_kernel<<<nb, 256, 0, stream>>>(cnt, part, Gr.nd);
    scan_part_kernel<<<1, 64, 0, stream>>>(part, nb);
    scan_final_kernel<<<nb, 256, 0, stream>>>(cnt, part, Gr.rowptr, Gr.nd);
    fill_i_kernel<<<(Gr.nd + 255) / 256, 256, 0, stream>>>(cnt, 0, Gr.nd);
    scatter_kernel<<<(Gr.ne + 255) / 256, 256, 0, stream>>>(Gr.src, Gr.dst, Gr.rowptr, cnt,
                                                            Gr.csr, Gr.ne);
  }

  // ---- one-time: attention vectors, packed bf16 weights, bf16 input states ----
  compute_v_kernel<<<8, 128, 0, stream>>>(Wsrc, att_src, vs);
  compute_v_kernel<<<8, 128, 0, stream>>>(Wdst, att_dst, vd);
  for (int g = 0; g < 8; ++g)
    pack_w_kernel<<<64, 256, 0, stream>>>(Wsrc + (size_t)g * 16384, wpack + (size_t)g * 16384);
  pack_w_kernel<<<64, 256, 0, stream>>>(W_ln, wpack + (size_t)8 * 16384);
  f2bf_kernel<<<(N_ACT * 16 + 255) / 256, 256, 0, stream>>>(x_act, xa0, N_ACT * 16);
  f2bf_kernel<<<(N_RS * 16 + 255) / 256, 256, 0, stream>>>(x_rs, xrs_b, N_RS * 16);
  f2bf_kernel<<<(N_RD * 16 + 255) / 256, 256, 0, stream>>>(x_rd, xrd0, N_RD * 16);

  const unsigned short* xa = xa0;
  unsigned short* xa_nxt = xa1;
  const unsigned short* xrd = xrd0;
  unsigned short* xrd_nxt = xrd1;

  for (int L = 0; L < 2; ++L) {
    // ---- all alphas for this layer: one pass per node type ----
    matvecN_kernel<4><<<(N_ACT + 3) / 4, 256, 0, stream>>>(
        xa, vs + (0 + L) * 128, vd + (0 + L) * 128, vs + (2 + L) * 128, vs + (6 + L) * 128,
        af_s, af_d, ars_s, ahrd_s, N_ACT);
    matvecN_kernel<3><<<(N_RD + 3) / 4, 256, 0, stream>>>(
        xrd, vs + (4 + L) * 128, vd + (4 + L) * 128, vd + (6 + L) * 128, nullptr,
        ard_s, ard_d, ahrd_d, nullptr, N_RD);
    matvecN_kernel<1><<<(N_RS + 3) / 4, 256, 0, stream>>>(
        xrs_b, vd + (2 + L) * 128, nullptr, nullptr, nullptr,
        ars_d, nullptr, nullptr, nullptr, N_RS);

    struct Rel {
      const unsigned short* xsh;
      int nd;
      const int* rowptr; const int* csr;
      const float* as; const float* ad;
      unsigned short* dsth; int mode;  // 0: relu->bf16, 1: f32 tmp (no relu), 2: +tmp, relu->bf16
    } rels[4] = {
      {xa, N_ACT, rowptr_f, csr_f, af_s, af_d, xa_nxt, 0},
      {xa, N_RS, rowptr_rs, csr_rs, ars_s, ars_d, xrs_b, 0},
      {xrd, N_RD, rowptr_rd, csr_rd, ard_s, ard_d, nullptr, 1},
      {xa, N_RD, rowptr_hrd, csr_hrd, ahrd_s, ahrd_d, xrd_nxt, 2},
    };

    for (int r = 0; r < 4; ++r) {
      const Rel& R = rels[r];
      int g = r * 2 + L;
      gat_aggr_kernel<<<(R.nd + 3) / 4, 256, 0, stream>>>(R.rowptr, R.csr, R.as, R.ad, R.xsh,
                                                          aggh, R.nd);
      const unsigned short* wp = wpack + (size_t)g * 16384;
      const float* bb = b_gat + g * 128;
      dim3 grid((R.nd + 127) / 128, 2);
      if (R.mode == 0)
        gemm_mfma_kernel<0, 1, 0><<<grid, 256, 0, stream>>>(aggh, wp, bb, nullptr, R.dsth,
                                                            nullptr, R.nd);
      else if (R.mode == 1)
        gemm_mfma_kernel<0, 0, 1><<<grid, 256, 0, stream>>>(aggh, wp, bb, nullptr, nullptr,
                                                            tmp, R.nd);
      else
        gemm_mfma_kernel<1, 1, 0><<<grid, 256, 0, stream>>>(aggh, wp, bb, tmp, R.dsth,
                                                            nullptr, R.nd);
    }

    // swap state buffers
    const unsigned short* t1 = xa; xa = xa_nxt; xa_nxt = (unsigned short*)t1;
    const unsigned short* t2 = xrd; xrd = xrd_nxt; xrd_nxt = (unsigned short*)t2;
  }

  fill_f_kernel<<<2, 256, 0, stream>>>(feats, 0.f, 384);
  const unsigned short* wpl = wpack + (size_t)8 * 16384;
  head_mfma_kernel<<<dim3((N_ACT + 511) / 512, 2), 256, 0, stream>>>(xa, wpl, b_ln, feats, N_ACT);
  head_mfma_kernel<<<dim3((N_RS + 511) / 512, 2), 256, 0, stream>>>(xrs_b, wpl, b_ln, feats + 128, N_RS);
  head_mfma_kernel<<<dim3((N_RD + 511) / 512, 2), 256, 0, stream>>>(xrd, wpl, b_ln, feats + 256, N_RD);
  final_fc_kernel<<<1, 128, 0, stream>>>(feats, feats + 128, feats + 256, W_fc, b_fc, out);
}

// Round 7
// 1161.399 us; speedup vs baseline: 4.8069x; 1.0919x over previous
//
#include <hip/hip_runtime.h>
#include <cmath>

#define HID 128

typedef __attribute__((ext_vector_type(8))) short bf16x8;
typedef __attribute__((ext_vector_type(4))) float f32x4;

__device__ inline unsigned short f2bf_rne(float f) {
  unsigned int b = __float_as_uint(f);
  return (unsigned short)((b + 0x7fffu + ((b >> 16) & 1u)) >> 16);
}
__device__ inline float bf2f(unsigned int u) { return __uint_as_float(u << 16); }

// ---------------- utility kernels ----------------

__global__ void fill_f_kernel(float* p, float v, int n) {
  int i = blockIdx.x * 256 + threadIdx.x;
  if (i < n) p[i] = v;
}

__global__ void fill_i_kernel(int* p, int v, int n) {
  int i = blockIdx.x * 256 + threadIdx.x;
  if (i < n) p[i] = v;
}

// fp32 -> bf16 (RNE), 8 elements per thread
__global__ void f2bf_kernel(const float* __restrict__ in, unsigned short* __restrict__ out,
                            int n8) {
  int i = blockIdx.x * 256 + threadIdx.x;
  if (i >= n8) return;
  const float4* p4 = reinterpret_cast<const float4*>(in) + (size_t)i * 2;
  float4 v0 = p4[0], v1 = p4[1];
  float vv[8] = {v0.x, v0.y, v0.z, v0.w, v1.x, v1.y, v1.z, v1.w};
  unsigned int r[8];
#pragma unroll
  for (int j = 0; j < 8; ++j) r[j] = f2bf_rne(vv[j]);
  uint4 o;
  o.x = r[0] | (r[1] << 16);
  o.y = r[2] | (r[3] << 16);
  o.z = r[4] | (r[5] << 16);
  o.w = r[6] | (r[7] << 16);
  reinterpret_cast<uint4*>(out)[i] = o;
}

// pack one 128x128 fp32 W (row-major [k][col]) into MFMA B-fragment order, bf16.
__global__ void pack_w_kernel(const float* __restrict__ W, unsigned short* __restrict__ Wp) {
  int o = blockIdx.x * 256 + threadIdx.x;
  if (o >= 16384) return;
  int j = o & 7;
  int lane = (o >> 3) & 63;
  int kk = (o >> 9) & 3;
  int ct = (o >> 11) & 3;
  int half = (o >> 13) & 1;
  int k = kk * 32 + ((lane >> 4) * 8) + j;
  int col = half * 64 + ct * 16 + (lane & 15);
  Wp[o] = f2bf_rne(W[k * 128 + col]);
}

// v[g][k] = sum_c W[g][k][c] * a[g][c]   (g = rel*2 + layer, 8 groups)
__global__ void compute_v_kernel(const float* __restrict__ W, const float* __restrict__ a,
                                 float* __restrict__ v) {
  int g = blockIdx.x, k = threadIdx.x;
  const float* Wg = W + g * 16384;
  const float* ag = a + g * 128;
  float s = 0.f;
  for (int c = 0; c < 128; ++c) s = fmaf(Wg[k * 128 + c], ag[c], s);
  v[g * 128 + k] = s;
}

// up to 4 dot products per row in ONE pass over bf16 X
template <int NV>
__global__ __launch_bounds__(256) void matvecN_kernel(
    const unsigned short* __restrict__ X, const float* __restrict__ v0,
    const float* __restrict__ v1, const float* __restrict__ v2, const float* __restrict__ v3,
    float* __restrict__ o0, float* __restrict__ o1, float* __restrict__ o2,
    float* __restrict__ o3, int N) {
  __shared__ float vl[NV][128];
  int tid = threadIdx.x;
  if (tid < 128) {
    vl[0][tid] = v0[tid];
    if (NV > 1) vl[1][tid] = v1[tid];
    if (NV > 2) vl[2][tid] = v2[tid];
    if (NV > 3) vl[3][tid] = v3[tid];
  }
  __syncthreads();
  int wave = tid >> 6, lane = tid & 63;
  int row = blockIdx.x * 4 + wave;
  if (row >= N) return;
  unsigned int u = *reinterpret_cast<const unsigned int*>(X + (size_t)row * 128 + lane * 2);
  float x0 = bf2f(u & 0xffffu), x1 = bf2f(u >> 16);
  float a[NV];
#pragma unroll
  for (int j = 0; j < NV; ++j) a[j] = x0 * vl[j][lane * 2] + x1 * vl[j][lane * 2 + 1];
#pragma unroll
  for (int j = 0; j < NV; ++j) {
    float s = a[j];
#pragma unroll
    for (int off = 32; off >= 1; off >>= 1) s += __shfl_down(s, off);
    a[j] = s;
  }
  if (lane == 0) {
    o0[row] = a[0];
    if (NV > 1) o1[row] = a[1];
    if (NV > 2) o2[row] = a[2];
    if (NV > 3) o3[row] = a[3];
  }
}

// max of |x| over 4 arrays (blockIdx.y selects), atomicMax on uint (fabs bits are ordered)
__global__ void max4_kernel(const float* __restrict__ a0, const float* __restrict__ a1,
                            const float* __restrict__ a2, const float* __restrict__ a3,
                            int n0, int n1, int n2, int n3, unsigned int* __restrict__ outm) {
  int y = blockIdx.y;
  const float* a = (y == 0) ? a0 : (y == 1) ? a1 : (y == 2) ? a2 : a3;
  int n = (y == 0) ? n0 : (y == 1) ? n1 : (y == 2) ? n2 : n3;
  float m = 0.f;
  for (int i = blockIdx.x * 256 + threadIdx.x; i < n; i += gridDim.x * 256)
    m = fmaxf(m, fabsf(a[i]));
#pragma unroll
  for (int off = 32; off >= 1; off >>= 1) m = fmaxf(m, __shfl_xor(m, off));
  if ((threadIdx.x & 63) == 0) atomicMax(&outm[y], __float_as_uint(m));
}

// ---------------- fused CSR build over 4 concatenated graphs ----------------
// dst-space offsets: f:0, rs:100000, rd:120000, hrd:170000 ; NDTOT=220000
// edge bases: f:0 (1.6M), rs:1.6M (0.8M), rd:2.4M (0.8M), hrd:3.2M (0.8M); ETOT=4M

__global__ void hist4_kernel(const int* __restrict__ d0, const int* __restrict__ d1,
                             const int* __restrict__ d2, const int* __restrict__ d3,
                             int* __restrict__ cnt_cat) {
  int e = blockIdx.x * 256 + threadIdx.x;
  if (e >= 4000000) return;
  const int* dp; int base, doff;
  if (e < 1600000)      { dp = d0; base = 0;       doff = 0; }
  else if (e < 2400000) { dp = d1; base = 1600000; doff = 100000; }
  else if (e < 3200000) { dp = d2; base = 2400000; doff = 120000; }
  else                  { dp = d3; base = 3200000; doff = 170000; }
  atomicAdd(&cnt_cat[doff + dp[e - base]], 1);
}

__global__ void scatter4_kernel(const int* __restrict__ s0, const int* __restrict__ d0,
                                const int* __restrict__ s1, const int* __restrict__ d1,
                                const int* __restrict__ s2, const int* __restrict__ d2,
                                const int* __restrict__ s3, const int* __restrict__ d3,
                                const int* __restrict__ rowptr_cat, int* __restrict__ fill_cat,
                                int* __restrict__ csr_cat) {
  int e = blockIdx.x * 256 + threadIdx.x;
  if (e >= 4000000) return;
  const int* sp; const int* dp; int base, doff;
  if (e < 1600000)      { sp = s0; dp = d0; base = 0;       doff = 0; }
  else if (e < 2400000) { sp = s1; dp = d1; base = 1600000; doff = 100000; }
  else if (e < 3200000) { sp = s2; dp = d2; base = 2400000; doff = 120000; }
  else                  { sp = s3; dp = d3; base = 3200000; doff = 170000; }
  int i = e - base;
  int gd = doff + dp[i];
  int pos = rowptr_cat[gd] + atomicAdd(&fill_cat[gd], 1);
  csr_cat[pos] = sp[i];
}

__global__ void partial_sum_kernel(const int* __restrict__ cnt, int* __restrict__ part, int n) {
  __shared__ int tmp[256];
  int i = blockIdx.x * 256 + threadIdx.x;
  tmp[threadIdx.x] = (i < n) ? cnt[i] : 0;
  __syncthreads();
  for (int off = 128; off; off >>= 1) {
    if (threadIdx.x < off) tmp[threadIdx.x] += tmp[threadIdx.x + off];
    __syncthreads();
  }
  if (threadIdx.x == 0) part[blockIdx.x] = tmp[0];
}

__global__ void scan_part_kernel(int* part, int nb) {
  if (threadIdx.x == 0 && blockIdx.x == 0) {
    int run = 0;
    for (int b = 0; b < nb; ++b) {
      int t = part[b];
      part[b] = run;
      run += t;
    }
  }
}

__global__ void scan_final_kernel(const int* __restrict__ cnt, const int* __restrict__ part,
                                  int* __restrict__ rowptr, int n) {
  __shared__ int tmp[256];
  int tid = threadIdx.x;
  int i = blockIdx.x * 256 + tid;
  int v = (i < n) ? cnt[i] : 0;
  tmp[tid] = v;
  __syncthreads();
  for (int off = 1; off < 256; off <<= 1) {
    int t = (tid >= off) ? tmp[tid - off] : 0;
    __syncthreads();
    tmp[tid] += t;
    __syncthreads();
  }
  if (i <= n) rowptr[i] = part[blockIdx.x] + tmp[tid] - v;  // exclusive; i==n -> ETOT
}

// ---------------- GAT aggregation: conservative-max softmax, LDS broadcast ----------------
// p = exp(e - mhat) with mhat = lrelu(max|as| + ad[d]) >= all e  (shift-invariant softmax)
__global__ __launch_bounds__(256) void gat_aggr_kernel(
    const int* __restrict__ rowptr, const int* __restrict__ csr, const float* __restrict__ as_,
    const float* __restrict__ ad_, const unsigned int* __restrict__ asmax, int midx,
    const unsigned short* __restrict__ Xh, unsigned short* __restrict__ aggh, int n_dst) {
  __shared__ float2 sp[4][64];
  int wave = threadIdx.x >> 6, lane = threadIdx.x & 63;
  int g = lane >> 4, li = lane & 15;
  int d = blockIdx.x * 4 + wave;
  if (d >= n_dst) return;
  int beg = rowptr[d], end = rowptr[d + 1];
  float ad = ad_[d];
  float t0 = __uint_as_float(asmax[midx]) + ad;
  float mh = t0 > 0.f ? t0 : 0.2f * t0;
  float z = 0.f;
  float a[8] = {};
  for (int c0 = beg; c0 < end; c0 += 64) {
    int j = c0 + lane;
    int s = 0;
    float p = 0.f;
    if (j < end) {
      s = csr[j];
      float t = as_[s] + ad;
      float e = t > 0.f ? t : 0.2f * t;
      p = __expf(e - mh);
      z += p;
    }
    sp[wave][lane] = make_float2(__int_as_float(s), p);
    asm volatile("s_waitcnt lgkmcnt(0)" ::: "memory");
    int cnt = min(64, end - c0);
    for (int k = 0; k < cnt; k += 4) {
      int idx = k + g;  // subgroup g handles edge k+g
      if (idx < cnt) {
        float2 w2 = sp[wave][idx];
        int s2 = __float_as_int(w2.x);
        float wgt = w2.y;
        const uint4 xv = *reinterpret_cast<const uint4*>(Xh + (size_t)s2 * 128 + li * 8);
        a[0] = fmaf(wgt, bf2f(xv.x & 0xffffu), a[0]);
        a[1] = fmaf(wgt, bf2f(xv.x >> 16), a[1]);
        a[2] = fmaf(wgt, bf2f(xv.y & 0xffffu), a[2]);
        a[3] = fmaf(wgt, bf2f(xv.y >> 16), a[3]);
        a[4] = fmaf(wgt, bf2f(xv.z & 0xffffu), a[4]);
        a[5] = fmaf(wgt, bf2f(xv.z >> 16), a[5]);
        a[6] = fmaf(wgt, bf2f(xv.w & 0xffffu), a[6]);
        a[7] = fmaf(wgt, bf2f(xv.w >> 16), a[7]);
      }
    }
  }
  // z: full 64-lane tree; a: sum the 4 subgroups
#pragma unroll
  for (int off = 32; off >= 1; off >>= 1) z += __shfl_xor(z, off);
#pragma unroll
  for (int i = 0; i < 8; ++i) {
    a[i] += __shfl_xor(a[i], 32);
    a[i] += __shfl_xor(a[i], 16);
  }
  if (g == 0) {
    float inv = 1.f / fmaxf(z, 1e-16f);
    uint4 o;
    o.x = (unsigned)f2bf_rne(a[0] * inv) | ((unsigned)f2bf_rne(a[1] * inv) << 16);
    o.y = (unsigned)f2bf_rne(a[2] * inv) | ((unsigned)f2bf_rne(a[3] * inv) << 16);
    o.z = (unsigned)f2bf_rne(a[4] * inv) | ((unsigned)f2bf_rne(a[5] * inv) << 16);
    o.w = (unsigned)f2bf_rne(a[6] * inv) | ((unsigned)f2bf_rne(a[7] * inv) << 16);
    *reinterpret_cast<uint4*>(aggh + (size_t)d * 128 + li * 8) = o;
  }
}

// ---------------- MFMA GEMM: out = [add +] X@W + bias [, relu] ----------------
template <int BETA, int RELU, int OUT32>
__global__ __launch_bounds__(256) void gemm_mfma_kernel(
    const unsigned short* __restrict__ X, const unsigned short* __restrict__ Wp,
    const float* __restrict__ bias, const float* __restrict__ add,
    unsigned short* __restrict__ Yh, float* __restrict__ Yf, int N) {
  int wid = threadIdx.x >> 6, lane = threadIdx.x & 63;
  int half = blockIdx.y;
  int r0 = blockIdx.x * 128 + wid * 32;
  int lr = lane & 15, gk = lane >> 4;
  bf16x8 b[4][4];
#pragma unroll
  for (int ct = 0; ct < 4; ++ct)
#pragma unroll
    for (int kk = 0; kk < 4; ++kk)
      b[ct][kk] = *reinterpret_cast<const bf16x8*>(Wp + ((((half * 4 + ct) * 4 + kk) * 64 + lane) << 3));
  f32x4 acc[2][4];
#pragma unroll
  for (int rt = 0; rt < 2; ++rt)
#pragma unroll
    for (int ct = 0; ct < 4; ++ct) acc[rt][ct] = (f32x4){0.f, 0.f, 0.f, 0.f};
  int row0 = r0 + lr, row1 = r0 + 16 + lr;
#pragma unroll
  for (int kk = 0; kk < 4; ++kk) {
    bf16x8 a0 = {}, a1 = {};
    if (row0 < N) a0 = *reinterpret_cast<const bf16x8*>(X + (size_t)row0 * 128 + kk * 32 + gk * 8);
    if (row1 < N) a1 = *reinterpret_cast<const bf16x8*>(X + (size_t)row1 * 128 + kk * 32 + gk * 8);
#pragma unroll
    for (int ct = 0; ct < 4; ++ct) {
      acc[0][ct] = __builtin_amdgcn_mfma_f32_16x16x32_bf16(a0, b[ct][kk], acc[0][ct], 0, 0, 0);
      acc[1][ct] = __builtin_amdgcn_mfma_f32_16x16x32_bf16(a1, b[ct][kk], acc[1][ct], 0, 0, 0);
    }
  }
#pragma unroll
  for (int rt = 0; rt < 2; ++rt)
#pragma unroll
    for (int ct = 0; ct < 4; ++ct) {
      int col = half * 64 + ct * 16 + lr;
      float bcol = bias[col];
#pragma unroll
      for (int reg = 0; reg < 4; ++reg) {
        int row = r0 + rt * 16 + gk * 4 + reg;
        if (row < N) {
          float o = acc[rt][ct][reg] + bcol;
          if (BETA) o += add[(size_t)row * 128 + col];
          if (RELU) o = fmaxf(o, 0.f);
          if (OUT32) Yf[(size_t)row * 128 + col] = o;
          else       Yh[(size_t)row * 128 + col] = f2bf_rne(o);
        }
      }
    }
}

// ---------------- MFMA head: feat[c] += sum_rows relu(X@W + b)[row][c] ----------------
__global__ __launch_bounds__(256) void head_mfma_kernel(
    const unsigned short* __restrict__ X, const unsigned short* __restrict__ Wp,
    const float* __restrict__ bias, float* __restrict__ feat, int N) {
  __shared__ float cs[64];
  int wid = threadIdx.x >> 6, lane = threadIdx.x & 63;
  int half = blockIdx.y;
  int lr = lane & 15, gk = lane >> 4;
  if (threadIdx.x < 64) cs[threadIdx.x] = 0.f;
  __syncthreads();
  bf16x8 b[4][4];
#pragma unroll
  for (int ct = 0; ct < 4; ++ct)
#pragma unroll
    for (int kk = 0; kk < 4; ++kk)
      b[ct][kk] = *reinterpret_cast<const bf16x8*>(Wp + ((((half * 4 + ct) * 4 + kk) * 64 + lane) << 3));
  float colsum[4] = {0.f, 0.f, 0.f, 0.f};
  for (int c = 0; c < 4; ++c) {
    int r0 = blockIdx.x * 512 + c * 128 + wid * 32;
    if (r0 >= N) break;
    f32x4 acc[2][4];
#pragma unroll
    for (int rt = 0; rt < 2; ++rt)
#pragma unroll
      for (int ct = 0; ct < 4; ++ct) acc[rt][ct] = (f32x4){0.f, 0.f, 0.f, 0.f};
    int row0 = r0 + lr, row1 = r0 + 16 + lr;
#pragma unroll
    for (int kk = 0; kk < 4; ++kk) {
      bf16x8 a0 = {}, a1 = {};
      if (row0 < N) a0 = *reinterpret_cast<const bf16x8*>(X + (size_t)row0 * 128 + kk * 32 + gk * 8);
      if (row1 < N) a1 = *reinterpret_cast<const bf16x8*>(X + (size_t)row1 * 128 + kk * 32 + gk * 8);
#pragma unroll
      for (int ct = 0; ct < 4; ++ct) {
        acc[0][ct] = __builtin_amdgcn_mfma_f32_16x16x32_bf16(a0, b[ct][kk], acc[0][ct], 0, 0, 0);
        acc[1][ct] = __builtin_amdgcn_mfma_f32_16x16x32_bf16(a1, b[ct][kk], acc[1][ct], 0, 0, 0);
      }
    }
#pragma unroll
    for (int rt = 0; rt < 2; ++rt)
#pragma unroll
      for (int ct = 0; ct < 4; ++ct) {
        float bcol = bias[half * 64 + ct * 16 + lr];
#pragma unroll
        for (int reg = 0; reg < 4; ++reg) {
          int row = r0 + rt * 16 + gk * 4 + reg;
          if (row < N) colsum[ct] += fmaxf(acc[rt][ct][reg] + bcol, 0.f);
        }
      }
  }
#pragma unroll
  for (int ct = 0; ct < 4; ++ct) {
    float v = colsum[ct];
    v += __shfl_xor(v, 16);
    v += __shfl_xor(v, 32);
    if (gk == 0) atomicAdd(&cs[ct * 16 + lr], v);
  }
  __syncthreads();
  if (threadIdx.x < 64) atomicAdd(&feat[half * 64 + threadIdx.x], cs[threadIdx.x]);
}

__global__ void final_fc_kernel(const float* __restrict__ fa, const float* __restrict__ frs,
                                const float* __restrict__ frd, const float* __restrict__ Wfc,
                                const float* __restrict__ bfc, float* __restrict__ out) {
  __shared__ float pooled[128];
  int t = threadIdx.x;
  if (t < 128)
    pooled[t] = (fa[t] * (1.f / 100000.f) + frs[t] * (1.f / 20000.f) + frd[t] * (1.f / 50000.f)) *
                (1.f / 3.f);
  __syncthreads();
  if (t < 64) {
    float s = bfc[t];
    for (int c = 0; c < 128; ++c) s = fmaf(pooled[c], Wfc[c * 64 + t], s);
    out[t] = s;
  }
}

// ---------------- orchestration ----------------

extern "C" void kernel_launch(void* const* d_in, const int* in_sizes, int n_in,
                              void* d_out, int out_size, void* d_ws, size_t ws_size,
                              hipStream_t stream) {
  const int N_ACT = 100000, N_RS = 20000, N_RD = 50000;
  const int NDTOT = 220000;           // 0 | 100000 | 120000 | 170000
  const int ETOT = 4000000;

  const float* x_act = (const float*)d_in[0];
  const float* x_rs = (const float*)d_in[1];
  const float* x_rd = (const float*)d_in[2];
  const int* ef_src = (const int*)d_in[3];
  const int* ef_dst = (const int*)d_in[4];
  const int* ers_src = (const int*)d_in[5];
  const int* ers_dst = (const int*)d_in[6];
  const int* erd_src = (const int*)d_in[7];
  const int* erd_dst = (const int*)d_in[8];
  const int* ehrd_src = (const int*)d_in[9];
  const int* ehrd_dst = (const int*)d_in[10];
  const float* Wsrc = (const float*)d_in[11];
  const float* Wdst = (const float*)d_in[12];
  const float* att_src = (const float*)d_in[13];
  const float* att_dst = (const float*)d_in[14];
  const float* b_gat = (const float*)d_in[15];
  const float* W_ln = (const float*)d_in[16];
  const float* b_ln = (const float*)d_in[17];
  const float* W_fc = (const float*)d_in[18];
  const float* b_fc = (const float*)d_in[19];
  float* out = (float*)d_out;

  // ---- workspace layout (~155 MB) ----
  float* w = (float*)d_ws;
  float* tmp = w;   w += (size_t)N_RD * 128;  // fp32 partial for the rd beta path
  float* af_s = w;   w += N_ACT;
  float* af_d = w;   w += N_ACT;
  float* ars_s = w;  w += N_ACT;
  float* ahrd_s = w; w += N_ACT;
  float* ard_s = w;  w += N_RD;
  float* ard_d = w;  w += N_RD;
  float* ahrd_d = w; w += N_RD;
  float* ars_d = w;  w += N_RS;
  float* vs = w;    w += 1024;
  float* vd = w;    w += 1024;
  float* feats = w; w += 384;
  unsigned int* asmax_u = (unsigned int*)w; w += 16;
  unsigned short* xa0 = (unsigned short*)w;   w += (size_t)N_ACT * 64;
  unsigned short* xa1 = (unsigned short*)w;   w += (size_t)N_ACT * 64;
  unsigned short* xrd0 = (unsigned short*)w;  w += (size_t)N_RD * 64;
  unsigned short* xrd1 = (unsigned short*)w;  w += (size_t)N_RD * 64;
  unsigned short* xrs_b = (unsigned short*)w; w += (size_t)N_RS * 64;
  unsigned short* aggh = (unsigned short*)w;  w += (size_t)N_ACT * 64;
  unsigned short* wpack = (unsigned short*)w; w += (9 * 16384) / 2;
  int* ip = (int*)w;
  int* cnt_cat = ip;    ip += NDTOT;        // cnt + fill adjacent -> single fill
  int* fill_cat = ip;   ip += NDTOT;
  int* rowptr_cat = ip; ip += NDTOT + 1;
  int* part = ip;       ip += 1024;
  int* csr_cat = ip;    ip += ETOT;

  // ---- fused CSR build over concatenated dst space ----
  fill_i_kernel<<<(2 * NDTOT + 255) / 256, 256, 0, stream>>>(cnt_cat, 0, 2 * NDTOT);
  hist4_kernel<<<(ETOT + 255) / 256, 256, 0, stream>>>(ef_dst, ers_dst, erd_dst, ehrd_dst,
                                                       cnt_cat);
  int nb = (NDTOT + 1 + 255) / 256;  // 860
  partial_sum_kernel<<<nb, 256, 0, stream>>>(cnt_cat, part, NDTOT);
  scan_part_kernel<<<1, 64, 0, stream>>>(part, nb);
  scan_final_kernel<<<nb, 256, 0, stream>>>(cnt_cat, part, rowptr_cat, NDTOT);
  scatter4_kernel<<<(ETOT + 255) / 256, 256, 0, stream>>>(
      ef_src, ef_dst, ers_src, ers_dst, erd_src, erd_dst, ehrd_src, ehrd_dst,
      rowptr_cat, fill_cat, csr_cat);

  // ---- one-time: attention vectors, packed bf16 weights, bf16 input states ----
  compute_v_kernel<<<8, 128, 0, stream>>>(Wsrc, att_src, vs);
  compute_v_kernel<<<8, 128, 0, stream>>>(Wdst, att_dst, vd);
  for (int g = 0; g < 8; ++g)
    pack_w_kernel<<<64, 256, 0, stream>>>(Wsrc + (size_t)g * 16384, wpack + (size_t)g * 16384);
  pack_w_kernel<<<64, 256, 0, stream>>>(W_ln, wpack + (size_t)8 * 16384);
  f2bf_kernel<<<(N_ACT * 16 + 255) / 256, 256, 0, stream>>>(x_act, xa0, N_ACT * 16);
  f2bf_kernel<<<(N_RS * 16 + 255) / 256, 256, 0, stream>>>(x_rs, xrs_b, N_RS * 16);
  f2bf_kernel<<<(N_RD * 16 + 255) / 256, 256, 0, stream>>>(x_rd, xrd0, N_RD * 16);

  const unsigned short* xa = xa0;
  unsigned short* xa_nxt = xa1;
  const unsigned short* xrd = xrd0;
  unsigned short* xrd_nxt = xrd1;

  for (int L = 0; L < 2; ++L) {
    // ---- all alphas for this layer ----
    matvecN_kernel<4><<<(N_ACT + 3) / 4, 256, 0, stream>>>(
        xa, vs + (0 + L) * 128, vd + (0 + L) * 128, vs + (2 + L) * 128, vs + (6 + L) * 128,
        af_s, af_d, ars_s, ahrd_s, N_ACT);
    matvecN_kernel<3><<<(N_RD + 3) / 4, 256, 0, stream>>>(
        xrd, vs + (4 + L) * 128, vd + (4 + L) * 128, vd + (6 + L) * 128, nullptr,
        ard_s, ard_d, ahrd_d, nullptr, N_RD);
    matvecN_kernel<1><<<(N_RS + 3) / 4, 256, 0, stream>>>(
        xrs_b, vd + (2 + L) * 128, nullptr, nullptr, nullptr,
        ars_d, nullptr, nullptr, nullptr, N_RS);

    // upper bounds max|as| per source-alpha array: {af_s, ars_s, ahrd_s, ard_s}
    fill_i_kernel<<<1, 64, 0, stream>>>((int*)asmax_u, 0, 4);
    max4_kernel<<<dim3(32, 4), 256, 0, stream>>>(af_s, ars_s, ahrd_s, ard_s,
                                                 N_ACT, N_ACT, N_ACT, N_RD, asmax_u);

    struct Rel {
      const unsigned short* xsh;
      int nd; int doff; int midx;
      const float* as; const float* ad;
      unsigned short* dsth; int mode;  // 0: relu->bf16, 1: f32 tmp, 2: +tmp relu->bf16
    } rels[4] = {
      {xa, N_ACT, 0,      0, af_s, af_d, xa_nxt, 0},
      {xa, N_RS,  100000, 1, ars_s, ars_d, xrs_b, 0},
      {xrd, N_RD, 120000, 3, ard_s, ard_d, nullptr, 1},
      {xa, N_RD,  170000, 2, ahrd_s, ahrd_d, xrd_nxt, 2},
    };

    for (int r = 0; r < 4; ++r) {
      const Rel& R = rels[r];
      int g = r * 2 + L;
      gat_aggr_kernel<<<(R.nd + 3) / 4, 256, 0, stream>>>(
          rowptr_cat + R.doff, csr_cat, R.as, R.ad, asmax_u, R.midx, R.xsh, aggh, R.nd);
      const unsigned short* wp = wpack + (size_t)g * 16384;
      const float* bb = b_gat + g * 128;
      dim3 grid((R.nd + 127) / 128, 2);
      if (R.mode == 0)
        gemm_mfma_kernel<0, 1, 0><<<grid, 256, 0, stream>>>(aggh, wp, bb, nullptr, R.dsth,
                                                            nullptr, R.nd);
      else if (R.mode == 1)
        gemm_mfma_kernel<0, 0, 1><<<grid, 256, 0, stream>>>(aggh, wp, bb, nullptr, nullptr,
                                                            tmp, R.nd);
      else
        gemm_mfma_kernel<1, 1, 0><<<grid, 256, 0, stream>>>(aggh, wp, bb, tmp, R.dsth,
                                                            nullptr, R.nd);
    }

    const unsigned short* t1 = xa; xa = xa_nxt; xa_nxt = (unsigned short*)t1;
    const unsigned short* t2 = xrd; xrd = xrd_nxt; xrd_nxt = (unsigned short*)t2;
  }

  fill_f_kernel<<<2, 256, 0, stream>>>(feats, 0.f, 384);
  const unsigned short* wpl = wpack + (size_t)8 * 16384;
  head_mfma_kernel<<<dim3((N_ACT + 511) / 512, 2), 256, 0, stream>>>(xa, wpl, b_ln, feats, N_ACT);
  head_mfma_kernel<<<dim3((N_RS + 511) / 512, 2), 256, 0, stream>>>(xrs_b, wpl, b_ln, feats + 128, N_RS);
  head_mfma_kernel<<<dim3((N_RD + 511) / 512, 2), 256, 0, stream>>>(xrd, wpl, b_ln, feats + 256, N_RD);
  final_fc_kernel<<<1, 128, 0, stream>>>(feats, feats + 128, feats + 256, W_fc, b_fc, out);
}